// Round 8
// baseline (620.513 us; speedup 1.0000x reference)
//
#include <hip/hip_runtime.h>

#define NROWS 4096
#define DDIM  128
#define NHEAD 8

typedef __attribute__((ext_vector_type(8))) short    short8;
typedef __attribute__((ext_vector_type(8))) _Float16 half8;
typedef __attribute__((ext_vector_type(4))) float    floatx4;

__device__ __forceinline__ float bf2f(unsigned short u){
  unsigned v = ((unsigned)u) << 16;
  return __builtin_bit_cast(float, v);
}
__device__ __forceinline__ unsigned short f2bf(float f){
  unsigned u = __builtin_bit_cast(unsigned, f);
  u += 0x7FFFu + ((u >> 16) & 1u);
  return (unsigned short)(u >> 16);
}
__device__ __forceinline__ void split2(float v, unsigned short& hi, unsigned short& lo){
  hi = f2bf(v);
  lo = f2bf(v - bf2f(hi));
}

// fp32 sentinels: 500=ws too small, 1000=in_sizes mismatch, 2000=launch fail.
__global__ void fill_kernel(float* __restrict__ out, float val, int n){
  int i = blockIdx.x * 256 + threadIdx.x;
  if (i < n) out[i] = val;
}
__global__ void zero_kernel(float* __restrict__ p, int n){
  int i = blockIdx.x * 256 + threadIdx.x;
  if (i < n) p[i] = 0.f;
}

// ---------------------------------------------------------------------------
// Kernel 1: k = x@Wk[h] -> fp16 row-major [h][n][d];
//           v = x@Wv[h] -> fp16 pre-transposed vt[h][tile][d][key&63].
// 3-term bf16 MFMA from fp32 inputs (24-bit effective product precision).
// grid (64 row-tiles, NHEAD, z: 0=k 1=v), block 256.
// ---------------------------------------------------------------------------
__global__ __launch_bounds__(256, 2) void proj_kernel(
    const float* __restrict__ x,
    const float* __restrict__ Wk, const float* __restrict__ Wv,
    _Float16* __restrict__ kh, _Float16* __restrict__ vt)
{
  __shared__ alignas(16) unsigned short wthi[DDIM][72];
  __shared__ alignas(16) unsigned short wtlo[DDIM][72];
  const int tid = threadIdx.x, lane = tid & 63, wave = tid >> 6;
  const int l4 = lane & 15, quad = lane >> 4;
  const int tile = blockIdx.x, h = blockIdx.y, z = blockIdx.z;
  const float* W = (z == 0 ? Wk : Wv) + h * DDIM * DDIM;

  floatx4 acc[8];
#pragma unroll
  for (int c = 0; c < 8; c++) acc[c] = (floatx4)0.f;

  for (int fh = 0; fh < 2; fh++) {
    for (int i = tid; i < DDIM * 64; i += 256) {
      const int d = i >> 6, fl = i & 63;
      unsigned short hi, lo;
      split2(W[(fh * 64 + fl) * DDIM + d], hi, lo);
      wthi[d][fl] = hi; wtlo[d][fl] = lo;
    }
    __syncthreads();

    const float* xr = x + (size_t)(tile * 64 + wave * 16 + l4) * DDIM + fh * 64 + quad * 8;
    short8 ah[2], al[2];
#pragma unroll
    for (int t2 = 0; t2 < 2; t2++) {
      float4 v0 = *(const float4*)(xr + t2 * 32);
      float4 v1 = *(const float4*)(xr + t2 * 32 + 4);
      float xv[8] = {v0.x, v0.y, v0.z, v0.w, v1.x, v1.y, v1.z, v1.w};
#pragma unroll
      for (int j = 0; j < 8; j++) {
        unsigned short hi, lo; split2(xv[j], hi, lo);
        ah[t2][j] = (short)hi; al[t2][j] = (short)lo;
      }
    }
#pragma unroll
    for (int t2 = 0; t2 < 2; t2++) {
#pragma unroll
      for (int c = 0; c < 8; c++) {
        short8 bh = *(const short8*)(&wthi[c * 16 + l4][t2 * 32 + quad * 8]);
        short8 bl = *(const short8*)(&wtlo[c * 16 + l4][t2 * 32 + quad * 8]);
        acc[c] = __builtin_amdgcn_mfma_f32_16x16x32_bf16(ah[t2], bh, acc[c], 0, 0, 0);
        acc[c] = __builtin_amdgcn_mfma_f32_16x16x32_bf16(al[t2], bh, acc[c], 0, 0, 0);
        acc[c] = __builtin_amdgcn_mfma_f32_16x16x32_bf16(ah[t2], bl, acc[c], 0, 0, 0);
      }
    }
    __syncthreads();
  }

  const int rb = wave * 16 + quad * 4;
#pragma unroll
  for (int c = 0; c < 8; c++) {
    const int d = c * 16 + l4;
#pragma unroll
    for (int r = 0; r < 4; r++) {
      const int n = tile * 64 + rb + r;
      const float val = acc[c][r];
      if (z == 0) kh[((size_t)h * NROWS + n) * DDIM + d] = (_Float16)val;
      else        vt[(((size_t)(h * 64 + tile) * DDIM + d) << 6) + (size_t)(rb + r)] = (_Float16)val;
    }
  }
}

// ---------------------------------------------------------------------------
// Kernel 2: flash attention. grid 512; h = bid & 7 (XCD-affine: all 64 blocks
// of a head share one XCD's L2, k+v = 2.1 MB < 4 MB), qt = bid >> 3.
// Phase 1: q = x@Wq[h] in-block (3-term bf16 MFMA), split to fp16 A-frags.
// kt loop (ZERO barriers): K/V B-frags read straight from global (L2-served,
// line-complete 16B/lane); S/PV in f16 MFMA; per-wave register softmax;
// P round-trips through wave-private LDS (no sync needed).
// Epilogue: fp32 atomicAdd of Wm[h]/l-scaled O into u. LDS union = 36864 B.
// ---------------------------------------------------------------------------
union FlashLds {
  struct { unsigned short hi[DDIM][72], lo[DDIM][72]; } wq;  // 36864 B
  float qf[64][132];                                         // 33792 B
  _Float16 p[4][16][72];                                     //  9216 B
};

__global__ __launch_bounds__(256, 4) void flash_kernel(
    const float* __restrict__ x, const float* __restrict__ Wq,
    const _Float16* __restrict__ kh, const _Float16* __restrict__ vt,
    const float* __restrict__ Wm, float* __restrict__ u)
{
  __shared__ alignas(16) FlashLds lds;
  const int tid = threadIdx.x, lane = tid & 63, wave = tid >> 6;
  const int l4 = lane & 15, quad = lane >> 4;
  const int h = blockIdx.x & 7, qt = blockIdx.x >> 3;
  const int q0 = qt * 64;

  // ---- phase 1: q = x @ Wq[h] for this block's 64 rows ----
  floatx4 qacc[8];
#pragma unroll
  for (int c = 0; c < 8; c++) qacc[c] = (floatx4)0.f;
  {
    const float* Wqh = Wq + h * DDIM * DDIM;
    for (int fh = 0; fh < 2; fh++) {
      for (int i = tid; i < DDIM * 64; i += 256) {
        const int d = i >> 6, fl = i & 63;
        unsigned short hi, lo;
        split2(Wqh[(fh * 64 + fl) * DDIM + d], hi, lo);
        lds.wq.hi[d][fl] = hi; lds.wq.lo[d][fl] = lo;
      }
      __syncthreads();
      const float* xr = x + (size_t)(q0 + wave * 16 + l4) * DDIM + fh * 64 + quad * 8;
      short8 ah[2], al[2];
#pragma unroll
      for (int t2 = 0; t2 < 2; t2++) {
        float4 v0 = *(const float4*)(xr + t2 * 32);
        float4 v1 = *(const float4*)(xr + t2 * 32 + 4);
        float xv[8] = {v0.x, v0.y, v0.z, v0.w, v1.x, v1.y, v1.z, v1.w};
#pragma unroll
        for (int j = 0; j < 8; j++) {
          unsigned short hi, lo; split2(xv[j], hi, lo);
          ah[t2][j] = (short)hi; al[t2][j] = (short)lo;
        }
      }
#pragma unroll
      for (int t2 = 0; t2 < 2; t2++) {
#pragma unroll
        for (int c = 0; c < 8; c++) {
          short8 bh = *(const short8*)(&lds.wq.hi[c * 16 + l4][t2 * 32 + quad * 8]);
          short8 bl = *(const short8*)(&lds.wq.lo[c * 16 + l4][t2 * 32 + quad * 8]);
          qacc[c] = __builtin_amdgcn_mfma_f32_16x16x32_bf16(ah[t2], bh, qacc[c], 0, 0, 0);
          qacc[c] = __builtin_amdgcn_mfma_f32_16x16x32_bf16(al[t2], bh, qacc[c], 0, 0, 0);
          qacc[c] = __builtin_amdgcn_mfma_f32_16x16x32_bf16(ah[t2], bl, qacc[c], 0, 0, 0);
        }
      }
      __syncthreads();
    }
  }
  // q: C-layout -> LDS fp32 -> fp16 A-frags
#pragma unroll
  for (int c = 0; c < 8; c++)
#pragma unroll
    for (int r = 0; r < 4; r++)
      lds.qf[wave * 16 + quad * 4 + r][c * 16 + l4] = qacc[c][r];
  __syncthreads();
  half8 aq[4];
#pragma unroll
  for (int t = 0; t < 4; t++) {
    float4 v0 = *(const float4*)(&lds.qf[wave * 16 + l4][t * 32 + quad * 8]);
    float4 v1 = *(const float4*)(&lds.qf[wave * 16 + l4][t * 32 + quad * 8 + 4]);
    aq[t][0] = (_Float16)v0.x; aq[t][1] = (_Float16)v0.y;
    aq[t][2] = (_Float16)v0.z; aq[t][3] = (_Float16)v0.w;
    aq[t][4] = (_Float16)v1.x; aq[t][5] = (_Float16)v1.y;
    aq[t][6] = (_Float16)v1.z; aq[t][7] = (_Float16)v1.w;
  }
  __syncthreads();  // qf reads done; p region may now be used

  // ---- kt loop: no barriers ----
  float m_run[4], l_run[4];
#pragma unroll
  for (int r = 0; r < 4; r++) { m_run[r] = -1e30f; l_run[r] = 0.f; }
  floatx4 Oacc[8];
#pragma unroll
  for (int c = 0; c < 8; c++) Oacc[c] = (floatx4)0.f;

  const _Float16* khh = kh + (size_t)h * NROWS * DDIM;   // [key][d]
  const _Float16* vth = vt + (size_t)h * 64 * DDIM * 64; // [kt][d][key64]

  for (int kt = 0; kt < 64; ++kt) {
    // S = Q @ K^T : B-frags straight from global (L2)
    floatx4 Sf[4];
#pragma unroll
    for (int c = 0; c < 4; c++) Sf[c] = (floatx4)0.f;
#pragma unroll
    for (int t = 0; t < 4; t++) {
      half8 b[4];
#pragma unroll
      for (int c = 0; c < 4; c++)
        b[c] = *(const half8*)(khh + (size_t)(kt * 64 + c * 16 + l4) * DDIM + t * 32 + quad * 8);
#pragma unroll
      for (int c = 0; c < 4; c++)
        Sf[c] = __builtin_amdgcn_mfma_f32_16x16x32_f16(aq[t], b[c], Sf[c], 0, 0, 0);
    }

    // per-wave register softmax (lane: row=quad*4+r, key=c*16+l4)
    float mt[4];
#pragma unroll
    for (int r = 0; r < 4; r++)
      mt[r] = fmaxf(fmaxf(Sf[0][r], Sf[1][r]), fmaxf(Sf[2][r], Sf[3][r]));
#pragma unroll
    for (int mk = 1; mk <= 8; mk <<= 1)
#pragma unroll
      for (int r = 0; r < 4; r++) mt[r] = fmaxf(mt[r], __shfl_xor(mt[r], mk, 64));

    float alpha[4];
#pragma unroll
    for (int r = 0; r < 4; r++) {
      const float mn = fmaxf(m_run[r], mt[r]);
      alpha[r] = __expf(m_run[r] - mn);
      m_run[r] = mn;
    }
    float pf[4][4], lsum[4];
#pragma unroll
    for (int r = 0; r < 4; r++) {
#pragma unroll
      for (int c = 0; c < 4; c++) pf[c][r] = __expf(Sf[c][r] - m_run[r]);
      lsum[r] = (pf[0][r] + pf[1][r]) + (pf[2][r] + pf[3][r]);
    }
#pragma unroll
    for (int mk = 1; mk <= 8; mk <<= 1)
#pragma unroll
      for (int r = 0; r < 4; r++) lsum[r] += __shfl_xor(lsum[r], mk, 64);
#pragma unroll
    for (int r = 0; r < 4; r++) l_run[r] = l_run[r] * alpha[r] + lsum[r];

    // P: C-layout -> A-layout via wave-private LDS (no block barrier needed)
#pragma unroll
    for (int c = 0; c < 4; c++)
#pragma unroll
      for (int r = 0; r < 4; r++)
        lds.p[wave][quad * 4 + r][c * 16 + l4] = (_Float16)pf[c][r];

    // rescale O, then O += P @ V (V B-frags from global)
#pragma unroll
    for (int c = 0; c < 8; c++) {
      Oacc[c][0] *= alpha[0]; Oacc[c][1] *= alpha[1];
      Oacc[c][2] *= alpha[2]; Oacc[c][3] *= alpha[3];
    }
#pragma unroll
    for (int t = 0; t < 2; t++) {
      half8 ap = *(const half8*)(&lds.p[wave][l4][t * 32 + quad * 8]);
#pragma unroll
      for (int c = 0; c < 8; c++) {
        half8 bv = *(const half8*)(vth + ((size_t)kt * DDIM + c * 16 + l4) * 64 + t * 32 + quad * 8);
        Oacc[c] = __builtin_amdgcn_mfma_f32_16x16x32_f16(ap, bv, Oacc[c], 0, 0, 0);
      }
    }
  }

  // epilogue: u[n][d] += Wm[h] * O / l  (fp32 atomics)
  {
    const float wmf = Wm[h];
    float inv[4];
#pragma unroll
    for (int r = 0; r < 4; r++) inv[r] = wmf / l_run[r];
    const int rbase = wave * 16 + quad * 4;
#pragma unroll
    for (int c = 0; c < 8; c++) {
      const int col = c * 16 + l4;
#pragma unroll
      for (int r = 0; r < 4; r++)
        atomicAdd(&u[(size_t)(q0 + rbase + r) * DDIM + col], Oacc[c][r] * inv[r]);
    }
  }
}

// ---------------------------------------------------------------------------
// Kernel 3: y = x + relu((x+u) @ Wg^T + bg), fp32 VALU. grid 2048 x 256.
// ---------------------------------------------------------------------------
__global__ __launch_bounds__(256) void mlp_kernel(
    const float* __restrict__ x, const float* __restrict__ u,
    const float* __restrict__ Wg, const float* __restrict__ bg,
    float* __restrict__ out)
{
  __shared__ float h_s[2][DDIM];
  const int t = threadIdx.x, i = t & 127, r = t >> 7;
  const int n = blockIdx.x * 2 + r;
  h_s[r][i] = x[(size_t)n * DDIM + i] + u[(size_t)n * DDIM + i];
  __syncthreads();
  float g = 0.f;
  for (int j = 0; j < DDIM; j++)
    g += h_s[r][j] * Wg[i * DDIM + j];
  out[(size_t)n * DDIM + i] = x[(size_t)n * DDIM + i] + fmaxf(g + bg[i], 0.f);
}

extern "C" void kernel_launch(void* const* d_in, const int* in_sizes, int n_in,
                              void* d_out, int out_size, void* d_ws, size_t ws_size,
                              hipStream_t stream) {
  float* out = (float*)d_out;
  const int fill_blocks = (out_size + 255) / 256;

  const bool ok_sizes =
      n_in == 7 &&
      in_sizes[0] == NROWS * DDIM &&
      in_sizes[1] == NHEAD * DDIM * DDIM &&
      in_sizes[2] == NHEAD * DDIM * DDIM &&
      in_sizes[3] == NHEAD * DDIM * DDIM &&
      in_sizes[4] == NHEAD &&
      in_sizes[5] == DDIM * DDIM &&
      in_sizes[6] == DDIM &&
      out_size == NROWS * DDIM;
  if (!ok_sizes) {
    fill_kernel<<<fill_blocks, 256, 0, stream>>>(out, 1000.f, out_size);
    return;
  }

  // ws: u fp32 (2MB) + kh fp16 (8.4MB) + vt fp16 (8.4MB) = 18.8MB
  const size_t HND = (size_t)NHEAD * NROWS * DDIM;
  const size_t need = (size_t)NROWS * DDIM * 4 + 2 * HND * 2;
  if (ws_size < need) {
    fill_kernel<<<fill_blocks, 256, 0, stream>>>(out, 500.f, out_size);
    return;
  }

  const float* x  = (const float*)d_in[0];
  const float* Wk = (const float*)d_in[1];
  const float* Wq = (const float*)d_in[2];
  const float* Wv = (const float*)d_in[3];
  const float* Wm = (const float*)d_in[4];
  const float* Wg = (const float*)d_in[5];
  const float* bg = (const float*)d_in[6];

  float*     u  = (float*)d_ws;
  _Float16*  kh = (_Float16*)(u + (size_t)NROWS * DDIM);
  _Float16*  vt = kh + HND;

  (void)hipGetLastError();
  zero_kernel<<<dim3(2048), 256, 0, stream>>>(u, NROWS * DDIM);
  proj_kernel<<<dim3(64, NHEAD, 2), 256, 0, stream>>>(x, Wk, Wv, kh, vt);
  flash_kernel<<<dim3(512), 256, 0, stream>>>(x, Wq, kh, vt, Wm, u);
  mlp_kernel<<<dim3(2048), 256, 0, stream>>>(x, u, Wg, bg, out);
  if (hipGetLastError() != hipSuccess) {
    fill_kernel<<<fill_blocks, 256, 0, stream>>>(out, 2000.f, out_size);
  }
}

// Round 9
// 419.570 us; speedup vs baseline: 1.4789x; 1.4789x over previous
//
#include <hip/hip_runtime.h>

#define NROWS 4096
#define DDIM  128
#define NHEAD 8

typedef __attribute__((ext_vector_type(8))) short    short8;
typedef __attribute__((ext_vector_type(8))) _Float16 half8;
typedef __attribute__((ext_vector_type(4))) float    floatx4;

__device__ __forceinline__ float bf2f(unsigned short u){
  unsigned v = ((unsigned)u) << 16;
  return __builtin_bit_cast(float, v);
}
__device__ __forceinline__ unsigned short f2bf(float f){
  unsigned u = __builtin_bit_cast(unsigned, f);
  u += 0x7FFFu + ((u >> 16) & 1u);
  return (unsigned short)(u >> 16);
}
__device__ __forceinline__ void split2(float v, unsigned short& hi, unsigned short& lo){
  hi = f2bf(v);
  lo = f2bf(v - bf2f(hi));
}

// fp32 sentinels: 500=ws too small, 1000=in_sizes mismatch, 2000=launch fail.
__global__ void fill_kernel(float* __restrict__ out, float val, int n){
  int i = blockIdx.x * 256 + threadIdx.x;
  if (i < n) out[i] = val;
}
__global__ void zero_kernel(float* __restrict__ p, int n){
  int i = blockIdx.x * 256 + threadIdx.x;
  if (i < n) p[i] = 0.f;
}

// ---------------------------------------------------------------------------
// Kernel 1: k = x@Wk[h] -> fp16 row-major [h][n][d];
//           v = x@Wv[h] -> fp16 pre-transposed vt[h][tile][d][key&63].
// 3-term bf16 MFMA from fp32 inputs (24-bit effective product precision).
// grid (64 row-tiles, NHEAD, z: 0=k 1=v), block 256.
// ---------------------------------------------------------------------------
__global__ __launch_bounds__(256, 2) void proj_kernel(
    const float* __restrict__ x,
    const float* __restrict__ Wk, const float* __restrict__ Wv,
    _Float16* __restrict__ kh, _Float16* __restrict__ vt)
{
  __shared__ alignas(16) unsigned short wthi[DDIM][72];
  __shared__ alignas(16) unsigned short wtlo[DDIM][72];
  const int tid = threadIdx.x, lane = tid & 63, wave = tid >> 6;
  const int l4 = lane & 15, quad = lane >> 4;
  const int tile = blockIdx.x, h = blockIdx.y, z = blockIdx.z;
  const float* W = (z == 0 ? Wk : Wv) + h * DDIM * DDIM;

  floatx4 acc[8];
#pragma unroll
  for (int c = 0; c < 8; c++) acc[c] = (floatx4)0.f;

  for (int fh = 0; fh < 2; fh++) {
    for (int i = tid; i < DDIM * 64; i += 256) {
      const int d = i >> 6, fl = i & 63;
      unsigned short hi, lo;
      split2(W[(fh * 64 + fl) * DDIM + d], hi, lo);
      wthi[d][fl] = hi; wtlo[d][fl] = lo;
    }
    __syncthreads();

    const float* xr = x + (size_t)(tile * 64 + wave * 16 + l4) * DDIM + fh * 64 + quad * 8;
    short8 ah[2], al[2];
#pragma unroll
    for (int t2 = 0; t2 < 2; t2++) {
      float4 v0 = *(const float4*)(xr + t2 * 32);
      float4 v1 = *(const float4*)(xr + t2 * 32 + 4);
      float xv[8] = {v0.x, v0.y, v0.z, v0.w, v1.x, v1.y, v1.z, v1.w};
#pragma unroll
      for (int j = 0; j < 8; j++) {
        unsigned short hi, lo; split2(xv[j], hi, lo);
        ah[t2][j] = (short)hi; al[t2][j] = (short)lo;
      }
    }
#pragma unroll
    for (int t2 = 0; t2 < 2; t2++) {
#pragma unroll
      for (int c = 0; c < 8; c++) {
        short8 bh = *(const short8*)(&wthi[c * 16 + l4][t2 * 32 + quad * 8]);
        short8 bl = *(const short8*)(&wtlo[c * 16 + l4][t2 * 32 + quad * 8]);
        acc[c] = __builtin_amdgcn_mfma_f32_16x16x32_bf16(ah[t2], bh, acc[c], 0, 0, 0);
        acc[c] = __builtin_amdgcn_mfma_f32_16x16x32_bf16(al[t2], bh, acc[c], 0, 0, 0);
        acc[c] = __builtin_amdgcn_mfma_f32_16x16x32_bf16(ah[t2], bl, acc[c], 0, 0, 0);
      }
    }
    __syncthreads();
  }

  const int rb = wave * 16 + quad * 4;
#pragma unroll
  for (int c = 0; c < 8; c++) {
    const int d = c * 16 + l4;
#pragma unroll
    for (int r = 0; r < 4; r++) {
      const int n = tile * 64 + rb + r;
      const float val = acc[c][r];
      if (z == 0) kh[((size_t)h * NROWS + n) * DDIM + d] = (_Float16)val;
      else        vt[(((size_t)(h * 64 + tile) * DDIM + d) << 6) + (size_t)(rb + r)] = (_Float16)val;
    }
  }
}

// ---------------------------------------------------------------------------
// Kernel 2: flash attention. grid 512; h = bid & 7 (XCD-affine), qt = bid>>3.
// Phase 1: q = x@Wq[h] in-block (3-term bf16 MFMA) -> fp16 A-frags.
// kt loop (2 barriers): K/V staged to LDS in FRAGMENT ORDER (each lane's b128
// read is exactly contiguous; staging writes + frag reads hit the 8-access/
// bank floor -> conflict-free). S/PV f16 MFMA; per-wave register softmax;
// P in wave-private fragment-ordered LDS (no barrier, proven R8).
// LDS union = 40960 B exactly -> 4 blocks/CU.
// ---------------------------------------------------------------------------
union FlashLds {
  struct { unsigned short hi[DDIM][72], lo[DDIM][72]; } wq;  // 36864 B
  float qf[64][132];                                         // 33792 B
  struct {
    _Float16 k[4][4][16][4][8];   // [c][t][l4][quad][j] 16384 B
    _Float16 v[8][2][16][4][8];   // [c][t][l4][quad][j] 16384 B
    _Float16 p[4][1024];          // per-wave frag-ordered  8192 B
  } kv;                                                      // 40960 B
};

__global__ __launch_bounds__(256, 4) void flash_kernel(
    const float* __restrict__ x, const float* __restrict__ Wq,
    const _Float16* __restrict__ kh, const _Float16* __restrict__ vt,
    const float* __restrict__ Wm, float* __restrict__ u)
{
  __shared__ alignas(16) FlashLds lds;
  const int tid = threadIdx.x, lane = tid & 63, wave = tid >> 6;
  const int l4 = lane & 15, quad = lane >> 4;
  const int h = blockIdx.x & 7, qt = blockIdx.x >> 3;
  const int q0 = qt * 64;

  // ---- phase 1: q = x @ Wq[h] for this block's 64 rows ----
  floatx4 qacc[8];
#pragma unroll
  for (int c = 0; c < 8; c++) qacc[c] = (floatx4)0.f;
  {
    const float* Wqh = Wq + h * DDIM * DDIM;
    for (int fh = 0; fh < 2; fh++) {
      for (int i = tid; i < DDIM * 64; i += 256) {
        const int d = i >> 6, fl = i & 63;
        unsigned short hi, lo;
        split2(Wqh[(fh * 64 + fl) * DDIM + d], hi, lo);
        lds.wq.hi[d][fl] = hi; lds.wq.lo[d][fl] = lo;
      }
      __syncthreads();
      const float* xr = x + (size_t)(q0 + wave * 16 + l4) * DDIM + fh * 64 + quad * 8;
      short8 ah[2], al[2];
#pragma unroll
      for (int t2 = 0; t2 < 2; t2++) {
        float4 v0 = *(const float4*)(xr + t2 * 32);
        float4 v1 = *(const float4*)(xr + t2 * 32 + 4);
        float xv[8] = {v0.x, v0.y, v0.z, v0.w, v1.x, v1.y, v1.z, v1.w};
#pragma unroll
        for (int j = 0; j < 8; j++) {
          unsigned short hi, lo; split2(xv[j], hi, lo);
          ah[t2][j] = (short)hi; al[t2][j] = (short)lo;
        }
      }
#pragma unroll
      for (int t2 = 0; t2 < 2; t2++) {
#pragma unroll
        for (int c = 0; c < 8; c++) {
          short8 bh = *(const short8*)(&lds.wq.hi[c * 16 + l4][t2 * 32 + quad * 8]);
          short8 bl = *(const short8*)(&lds.wq.lo[c * 16 + l4][t2 * 32 + quad * 8]);
          qacc[c] = __builtin_amdgcn_mfma_f32_16x16x32_bf16(ah[t2], bh, qacc[c], 0, 0, 0);
          qacc[c] = __builtin_amdgcn_mfma_f32_16x16x32_bf16(al[t2], bh, qacc[c], 0, 0, 0);
          qacc[c] = __builtin_amdgcn_mfma_f32_16x16x32_bf16(ah[t2], bl, qacc[c], 0, 0, 0);
        }
      }
      __syncthreads();
    }
  }
  // q: C-layout -> LDS fp32 -> fp16 A-frags
#pragma unroll
  for (int c = 0; c < 8; c++)
#pragma unroll
    for (int r = 0; r < 4; r++)
      lds.qf[wave * 16 + quad * 4 + r][c * 16 + l4] = qacc[c][r];
  __syncthreads();
  half8 aq[4];
#pragma unroll
  for (int t = 0; t < 4; t++) {
    float4 v0 = *(const float4*)(&lds.qf[wave * 16 + l4][t * 32 + quad * 8]);
    float4 v1 = *(const float4*)(&lds.qf[wave * 16 + l4][t * 32 + quad * 8 + 4]);
    aq[t][0] = (_Float16)v0.x; aq[t][1] = (_Float16)v0.y;
    aq[t][2] = (_Float16)v0.z; aq[t][3] = (_Float16)v0.w;
    aq[t][4] = (_Float16)v1.x; aq[t][5] = (_Float16)v1.y;
    aq[t][6] = (_Float16)v1.z; aq[t][7] = (_Float16)v1.w;
  }
  __syncthreads();  // qf reads done; kv region may now be used

  // ---- kt loop: 2 barriers ----
  float m_run[4], l_run[4];
#pragma unroll
  for (int r = 0; r < 4; r++) { m_run[r] = -1e30f; l_run[r] = 0.f; }
  floatx4 Oacc[8];
#pragma unroll
  for (int c = 0; c < 8; c++) Oacc[c] = (floatx4)0.f;

  const _Float16* khh = kh + (size_t)h * NROWS * DDIM;   // [key][d]
  const _Float16* vth = vt + (size_t)h * 64 * DDIM * 64; // [kt][d][key64]

  for (int kt = 0; kt < 64; ++kt) {
    // ---- stage K and V tiles in fragment order ----
    {
      const _Float16* ksrc = khh + (size_t)kt * 64 * DDIM;
#pragma unroll
      for (int i = tid; i < 1024; i += 256) {
        const int r = i >> 4, d8 = i & 15;
        *(half8*)&lds.kv.k[r >> 4][d8 >> 2][r & 15][d8 & 3][0] =
            *(const half8*)(ksrc + r * DDIM + d8 * 8);
      }
      const _Float16* vsrc = vth + (size_t)kt * DDIM * 64;
#pragma unroll
      for (int i = tid; i < 1024; i += 256) {
        const int d = i >> 3, ch = i & 7;
        *(half8*)&lds.kv.v[d >> 4][ch >> 2][d & 15][ch & 3][0] =
            *(const half8*)(vsrc + d * 64 + ch * 8);
      }
    }
    __syncthreads();  // b1: tiles staged

    // ---- S = Q @ K^T ----
    floatx4 Sf[4];
#pragma unroll
    for (int c = 0; c < 4; c++) Sf[c] = (floatx4)0.f;
#pragma unroll
    for (int t = 0; t < 4; t++) {
      half8 b[4];
#pragma unroll
      for (int c = 0; c < 4; c++)
        b[c] = *(const half8*)&lds.kv.k[c][t][l4][quad][0];
#pragma unroll
      for (int c = 0; c < 4; c++)
        Sf[c] = __builtin_amdgcn_mfma_f32_16x16x32_f16(aq[t], b[c], Sf[c], 0, 0, 0);
    }

    // ---- per-wave register softmax (lane: row=quad*4+r, key=c*16+l4) ----
    float mt[4];
#pragma unroll
    for (int r = 0; r < 4; r++)
      mt[r] = fmaxf(fmaxf(Sf[0][r], Sf[1][r]), fmaxf(Sf[2][r], Sf[3][r]));
#pragma unroll
    for (int mk = 1; mk <= 8; mk <<= 1)
#pragma unroll
      for (int r = 0; r < 4; r++) mt[r] = fmaxf(mt[r], __shfl_xor(mt[r], mk, 64));

    float alpha[4];
#pragma unroll
    for (int r = 0; r < 4; r++) {
      const float mn = fmaxf(m_run[r], mt[r]);
      alpha[r] = __expf(m_run[r] - mn);
      m_run[r] = mn;
    }
    float lsum[4];
#pragma unroll
    for (int r = 0; r < 4; r++) {
#pragma unroll
      for (int c = 0; c < 4; c++) Sf[c][r] = __expf(Sf[c][r] - m_run[r]);
      lsum[r] = (Sf[0][r] + Sf[1][r]) + (Sf[2][r] + Sf[3][r]);
    }
#pragma unroll
    for (int mk = 1; mk <= 8; mk <<= 1)
#pragma unroll
      for (int r = 0; r < 4; r++) lsum[r] += __shfl_xor(lsum[r], mk, 64);
#pragma unroll
    for (int r = 0; r < 4; r++) l_run[r] = l_run[r] * alpha[r] + lsum[r];

    // ---- P: C-layout -> A-layout, wave-private fragment-ordered LDS ----
    // element (row, key): idx = ((key>>3)*16 + row)*8 + (key&7)
#pragma unroll
    for (int c = 0; c < 4; c++)
#pragma unroll
      for (int r = 0; r < 4; r++)
        lds.kv.p[wave][((c * 2 + (l4 >> 3)) * 16 + quad * 4 + r) * 8 + (l4 & 7)] =
            (_Float16)Sf[c][r];

    // ---- rescale O, then O += P @ V ----
#pragma unroll
    for (int c = 0; c < 8; c++) {
      Oacc[c][0] *= alpha[0]; Oacc[c][1] *= alpha[1];
      Oacc[c][2] *= alpha[2]; Oacc[c][3] *= alpha[3];
    }
#pragma unroll
    for (int t = 0; t < 2; t++) {
      half8 ap = *(const half8*)&lds.kv.p[wave][((t * 4 + quad) * 16 + l4) * 8];
#pragma unroll
      for (int c = 0; c < 8; c++) {
        half8 bv = *(const half8*)&lds.kv.v[c][t][l4][quad][0];
        Oacc[c] = __builtin_amdgcn_mfma_f32_16x16x32_f16(ap, bv, Oacc[c], 0, 0, 0);
      }
    }
    __syncthreads();  // b2: all reads done -> safe to restage
  }

  // ---- epilogue: u[n][d] += Wm[h] * O / l  (fp32 atomics) ----
  {
    const float wmf = Wm[h];
    float inv[4];
#pragma unroll
    for (int r = 0; r < 4; r++) inv[r] = wmf / l_run[r];
    const int rbase = wave * 16 + quad * 4;
#pragma unroll
    for (int c = 0; c < 8; c++) {
      const int col = c * 16 + l4;
#pragma unroll
      for (int r = 0; r < 4; r++)
        atomicAdd(&u[(size_t)(q0 + rbase + r) * DDIM + col], Oacc[c][r] * inv[r]);
    }
  }
}

// ---------------------------------------------------------------------------
// Kernel 3: y = x + relu((x+u) @ Wg^T + bg), fp32 VALU. grid 2048 x 256.
// ---------------------------------------------------------------------------
__global__ __launch_bounds__(256) void mlp_kernel(
    const float* __restrict__ x, const float* __restrict__ u,
    const float* __restrict__ Wg, const float* __restrict__ bg,
    float* __restrict__ out)
{
  __shared__ float h_s[2][DDIM];
  const int t = threadIdx.x, i = t & 127, r = t >> 7;
  const int n = blockIdx.x * 2 + r;
  h_s[r][i] = x[(size_t)n * DDIM + i] + u[(size_t)n * DDIM + i];
  __syncthreads();
  float g = 0.f;
  for (int j = 0; j < DDIM; j++)
    g += h_s[r][j] * Wg[i * DDIM + j];
  out[(size_t)n * DDIM + i] = x[(size_t)n * DDIM + i] + fmaxf(g + bg[i], 0.f);
}

extern "C" void kernel_launch(void* const* d_in, const int* in_sizes, int n_in,
                              void* d_out, int out_size, void* d_ws, size_t ws_size,
                              hipStream_t stream) {
  float* out = (float*)d_out;
  const int fill_blocks = (out_size + 255) / 256;

  const bool ok_sizes =
      n_in == 7 &&
      in_sizes[0] == NROWS * DDIM &&
      in_sizes[1] == NHEAD * DDIM * DDIM &&
      in_sizes[2] == NHEAD * DDIM * DDIM &&
      in_sizes[3] == NHEAD * DDIM * DDIM &&
      in_sizes[4] == NHEAD &&
      in_sizes[5] == DDIM * DDIM &&
      in_sizes[6] == DDIM &&
      out_size == NROWS * DDIM;
  if (!ok_sizes) {
    fill_kernel<<<fill_blocks, 256, 0, stream>>>(out, 1000.f, out_size);
    return;
  }

  // ws: u fp32 (2MB) + kh fp16 (8.4MB) + vt fp16 (8.4MB) = 18.8MB
  const size_t HND = (size_t)NHEAD * NROWS * DDIM;
  const size_t need = (size_t)NROWS * DDIM * 4 + 2 * HND * 2;
  if (ws_size < need) {
    fill_kernel<<<fill_blocks, 256, 0, stream>>>(out, 500.f, out_size);
    return;
  }

  const float* x  = (const float*)d_in[0];
  const float* Wk = (const float*)d_in[1];
  const float* Wq = (const float*)d_in[2];
  const float* Wv = (const float*)d_in[3];
  const float* Wm = (const float*)d_in[4];
  const float* Wg = (const float*)d_in[5];
  const float* bg = (const float*)d_in[6];

  float*     u  = (float*)d_ws;
  _Float16*  kh = (_Float16*)(u + (size_t)NROWS * DDIM);
  _Float16*  vt = kh + HND;

  (void)hipGetLastError();
  zero_kernel<<<dim3(2048), 256, 0, stream>>>(u, NROWS * DDIM);
  proj_kernel<<<dim3(64, NHEAD, 2), 256, 0, stream>>>(x, Wk, Wv, kh, vt);
  flash_kernel<<<dim3(512), 256, 0, stream>>>(x, Wq, kh, vt, Wm, u);
  mlp_kernel<<<dim3(2048), 256, 0, stream>>>(x, u, Wg, bg, out);
  if (hipGetLastError() != hipSuccess) {
    fill_kernel<<<fill_blocks, 256, 0, stream>>>(out, 2000.f, out_size);
  }
}

// Round 10
// 324.907 us; speedup vs baseline: 1.9098x; 1.2914x over previous
//
#include <hip/hip_runtime.h>

#define NROWS 4096
#define DDIM  128
#define NHEAD 8

typedef __attribute__((ext_vector_type(8))) short    short8;
typedef __attribute__((ext_vector_type(8))) _Float16 half8;
typedef __attribute__((ext_vector_type(4))) float    floatx4;

__device__ __forceinline__ float bf2f(unsigned short u){
  unsigned v = ((unsigned)u) << 16;
  return __builtin_bit_cast(float, v);
}
__device__ __forceinline__ unsigned short f2bf(float f){
  unsigned u = __builtin_bit_cast(unsigned, f);
  u += 0x7FFFu + ((u >> 16) & 1u);
  return (unsigned short)(u >> 16);
}
__device__ __forceinline__ void split2(float v, unsigned short& hi, unsigned short& lo){
  hi = f2bf(v);
  lo = f2bf(v - bf2f(hi));
}

// fp32 sentinels: 500=ws too small, 1000=in_sizes mismatch, 2000=launch fail.
__global__ void fill_kernel(float* __restrict__ out, float val, int n){
  int i = blockIdx.x * 256 + threadIdx.x;
  if (i < n) out[i] = val;
}

// ---------------------------------------------------------------------------
// Kernel 1: k = x@Wk[h] -> fp16 row-major [h][n][d];
//           v = x@Wv[h] -> fp16 pre-transposed vt[h][tile][d][key&63].
// 3-term bf16 MFMA from fp32 inputs. grid (64, NHEAD, 2), block 256.
// ---------------------------------------------------------------------------
__global__ __launch_bounds__(256, 2) void proj_kernel(
    const float* __restrict__ x,
    const float* __restrict__ Wk, const float* __restrict__ Wv,
    _Float16* __restrict__ kh, _Float16* __restrict__ vt)
{
  __shared__ alignas(16) unsigned short wthi[DDIM][72];
  __shared__ alignas(16) unsigned short wtlo[DDIM][72];
  const int tid = threadIdx.x, lane = tid & 63, wave = tid >> 6;
  const int l4 = lane & 15, quad = lane >> 4;
  const int tile = blockIdx.x, h = blockIdx.y, z = blockIdx.z;
  const float* W = (z == 0 ? Wk : Wv) + h * DDIM * DDIM;

  floatx4 acc[8];
#pragma unroll
  for (int c = 0; c < 8; c++) acc[c] = (floatx4)0.f;

  for (int fh = 0; fh < 2; fh++) {
    for (int i = tid; i < DDIM * 64; i += 256) {
      const int d = i >> 6, fl = i & 63;
      unsigned short hi, lo;
      split2(W[(fh * 64 + fl) * DDIM + d], hi, lo);
      wthi[d][fl] = hi; wtlo[d][fl] = lo;
    }
    __syncthreads();

    const float* xr = x + (size_t)(tile * 64 + wave * 16 + l4) * DDIM + fh * 64 + quad * 8;
    short8 ah[2], al[2];
#pragma unroll
    for (int t2 = 0; t2 < 2; t2++) {
      float4 v0 = *(const float4*)(xr + t2 * 32);
      float4 v1 = *(const float4*)(xr + t2 * 32 + 4);
      float xv[8] = {v0.x, v0.y, v0.z, v0.w, v1.x, v1.y, v1.z, v1.w};
#pragma unroll
      for (int j = 0; j < 8; j++) {
        unsigned short hi, lo; split2(xv[j], hi, lo);
        ah[t2][j] = (short)hi; al[t2][j] = (short)lo;
      }
    }
#pragma unroll
    for (int t2 = 0; t2 < 2; t2++) {
#pragma unroll
      for (int c = 0; c < 8; c++) {
        short8 bh = *(const short8*)(&wthi[c * 16 + l4][t2 * 32 + quad * 8]);
        short8 bl = *(const short8*)(&wtlo[c * 16 + l4][t2 * 32 + quad * 8]);
        acc[c] = __builtin_amdgcn_mfma_f32_16x16x32_bf16(ah[t2], bh, acc[c], 0, 0, 0);
        acc[c] = __builtin_amdgcn_mfma_f32_16x16x32_bf16(al[t2], bh, acc[c], 0, 0, 0);
        acc[c] = __builtin_amdgcn_mfma_f32_16x16x32_bf16(ah[t2], bl, acc[c], 0, 0, 0);
      }
    }
    __syncthreads();
  }

  const int rb = wave * 16 + quad * 4;
#pragma unroll
  for (int c = 0; c < 8; c++) {
    const int d = c * 16 + l4;
#pragma unroll
    for (int r = 0; r < 4; r++) {
      const int n = tile * 64 + rb + r;
      const float val = acc[c][r];
      if (z == 0) kh[((size_t)h * NROWS + n) * DDIM + d] = (_Float16)val;
      else        vt[(((size_t)(h * 64 + tile) * DDIM + d) << 6) + (size_t)(rb + r)] = (_Float16)val;
    }
  }
}

// ---------------------------------------------------------------------------
// Kernel 2: flash attention, SPLIT-K x2. grid 1024: h=bid&7 (XCD-affine),
// qt=(bid>>3)&63, s=bid>>9; block handles key tiles [s*32, s*32+32).
// Writes UNNORMALIZED partial O (fp16) + per-row (m,l) to ws; no atomics.
// l accumulated via ones-MFMA (P rowsum as a 9th output column) — no
// sum-shuffles in the loop. LDS union = 40960 B -> 4 blocks/CU.
// ---------------------------------------------------------------------------
union FlashLds {
  struct { unsigned short hi[DDIM][72], lo[DDIM][72]; } wq;  // 36864 B
  float qf[64][132];                                         // 33792 B
  struct {
    _Float16 k[4][4][16][4][8];   // [c][t][l4][quad][j] 16384 B
    _Float16 v[8][2][16][4][8];   // [c][t][l4][quad][j] 16384 B
    _Float16 p[4][1024];          // per-wave frag-ordered  8192 B
  } kv;                                                      // 40960 B
};

__global__ __launch_bounds__(256, 4) void flash_kernel(
    const float* __restrict__ x, const float* __restrict__ Wq,
    const _Float16* __restrict__ kh, const _Float16* __restrict__ vt,
    _Float16* __restrict__ op, float* __restrict__ mb, float* __restrict__ lb)
{
  __shared__ alignas(16) FlashLds lds;
  const int tid = threadIdx.x, lane = tid & 63, wave = tid >> 6;
  const int l4 = lane & 15, quad = lane >> 4;
  const int h = blockIdx.x & 7, qt = (blockIdx.x >> 3) & 63, s = blockIdx.x >> 9;
  const int q0 = qt * 64;

  // ---- phase 1: q = x @ Wq[h] for this block's 64 rows (3-term bf16) ----
  floatx4 qacc[8];
#pragma unroll
  for (int c = 0; c < 8; c++) qacc[c] = (floatx4)0.f;
  {
    const float* Wqh = Wq + h * DDIM * DDIM;
    for (int fh = 0; fh < 2; fh++) {
      for (int i = tid; i < DDIM * 64; i += 256) {
        const int d = i >> 6, fl = i & 63;
        unsigned short hi, lo;
        split2(Wqh[(fh * 64 + fl) * DDIM + d], hi, lo);
        lds.wq.hi[d][fl] = hi; lds.wq.lo[d][fl] = lo;
      }
      __syncthreads();
      const float* xr = x + (size_t)(q0 + wave * 16 + l4) * DDIM + fh * 64 + quad * 8;
      short8 ah[2], al[2];
#pragma unroll
      for (int t2 = 0; t2 < 2; t2++) {
        float4 v0 = *(const float4*)(xr + t2 * 32);
        float4 v1 = *(const float4*)(xr + t2 * 32 + 4);
        float xv[8] = {v0.x, v0.y, v0.z, v0.w, v1.x, v1.y, v1.z, v1.w};
#pragma unroll
        for (int j = 0; j < 8; j++) {
          unsigned short hi, lo; split2(xv[j], hi, lo);
          ah[t2][j] = (short)hi; al[t2][j] = (short)lo;
        }
      }
#pragma unroll
      for (int t2 = 0; t2 < 2; t2++) {
#pragma unroll
        for (int c = 0; c < 8; c++) {
          short8 bh = *(const short8*)(&lds.wq.hi[c * 16 + l4][t2 * 32 + quad * 8]);
          short8 bl = *(const short8*)(&lds.wq.lo[c * 16 + l4][t2 * 32 + quad * 8]);
          qacc[c] = __builtin_amdgcn_mfma_f32_16x16x32_bf16(ah[t2], bh, qacc[c], 0, 0, 0);
          qacc[c] = __builtin_amdgcn_mfma_f32_16x16x32_bf16(al[t2], bh, qacc[c], 0, 0, 0);
          qacc[c] = __builtin_amdgcn_mfma_f32_16x16x32_bf16(ah[t2], bl, qacc[c], 0, 0, 0);
        }
      }
      __syncthreads();
    }
  }
  // q: C-layout -> LDS fp32 -> fp16 A-frags
#pragma unroll
  for (int c = 0; c < 8; c++)
#pragma unroll
    for (int r = 0; r < 4; r++)
      lds.qf[wave * 16 + quad * 4 + r][c * 16 + l4] = qacc[c][r];
  __syncthreads();
  half8 aq[4];
#pragma unroll
  for (int t = 0; t < 4; t++) {
    float4 v0 = *(const float4*)(&lds.qf[wave * 16 + l4][t * 32 + quad * 8]);
    float4 v1 = *(const float4*)(&lds.qf[wave * 16 + l4][t * 32 + quad * 8 + 4]);
    aq[t][0] = (_Float16)v0.x; aq[t][1] = (_Float16)v0.y;
    aq[t][2] = (_Float16)v0.z; aq[t][3] = (_Float16)v0.w;
    aq[t][4] = (_Float16)v1.x; aq[t][5] = (_Float16)v1.y;
    aq[t][6] = (_Float16)v1.z; aq[t][7] = (_Float16)v1.w;
  }
  __syncthreads();  // qf reads done; kv region may now be used

  // ---- kt loop over this block's half of the keys ----
  float m_run[4];
#pragma unroll
  for (int r = 0; r < 4; r++) m_run[r] = -1e30f;
  floatx4 Oacc[8], lacc = (floatx4)0.f;
#pragma unroll
  for (int c = 0; c < 8; c++) Oacc[c] = (floatx4)0.f;

  half8 vones;
#pragma unroll
  for (int j = 0; j < 8; j++) vones[j] = (_Float16)1.f;

  const _Float16* khh = kh + (size_t)h * NROWS * DDIM;
  const _Float16* vth = vt + (size_t)h * 64 * DDIM * 64;

  for (int kt = s * 32; kt < s * 32 + 32; ++kt) {
    // ---- stage K and V tiles in fragment order ----
    {
      const _Float16* ksrc = khh + (size_t)kt * 64 * DDIM;
#pragma unroll
      for (int i = tid; i < 1024; i += 256) {
        const int r = i >> 4, d8 = i & 15;
        *(half8*)&lds.kv.k[r >> 4][d8 >> 2][r & 15][d8 & 3][0] =
            *(const half8*)(ksrc + r * DDIM + d8 * 8);
      }
      const _Float16* vsrc = vth + (size_t)kt * DDIM * 64;
#pragma unroll
      for (int i = tid; i < 1024; i += 256) {
        const int d = i >> 3, ch = i & 7;
        *(half8*)&lds.kv.v[d >> 4][ch >> 2][d & 15][ch & 3][0] =
            *(const half8*)(vsrc + d * 64 + ch * 8);
      }
    }
    __syncthreads();  // b1: tiles staged

    // ---- S = Q @ K^T ----
    floatx4 Sf[4];
#pragma unroll
    for (int c = 0; c < 4; c++) Sf[c] = (floatx4)0.f;
#pragma unroll
    for (int t = 0; t < 4; t++) {
      half8 b[4];
#pragma unroll
      for (int c = 0; c < 4; c++)
        b[c] = *(const half8*)&lds.kv.k[c][t][l4][quad][0];
#pragma unroll
      for (int c = 0; c < 4; c++)
        Sf[c] = __builtin_amdgcn_mfma_f32_16x16x32_f16(aq[t], b[c], Sf[c], 0, 0, 0);
    }

    // ---- per-wave register softmax: tile max + alpha ----
    float mt[4];
#pragma unroll
    for (int r = 0; r < 4; r++)
      mt[r] = fmaxf(fmaxf(Sf[0][r], Sf[1][r]), fmaxf(Sf[2][r], Sf[3][r]));
#pragma unroll
    for (int mk = 1; mk <= 8; mk <<= 1)
#pragma unroll
      for (int r = 0; r < 4; r++) mt[r] = fmaxf(mt[r], __shfl_xor(mt[r], mk, 64));

    float alpha[4];
#pragma unroll
    for (int r = 0; r < 4; r++) {
      const float mn = fmaxf(m_run[r], mt[r]);
      alpha[r] = __expf(m_run[r] - mn);
      m_run[r] = mn;
    }
#pragma unroll
    for (int r = 0; r < 4; r++)
#pragma unroll
      for (int c = 0; c < 4; c++) Sf[c][r] = __expf(Sf[c][r] - m_run[r]);

    // ---- P: C-layout -> A-layout, wave-private fragment-ordered LDS ----
#pragma unroll
    for (int c = 0; c < 4; c++)
#pragma unroll
      for (int r = 0; r < 4; r++)
        lds.kv.p[wave][((c * 2 + (l4 >> 3)) * 16 + quad * 4 + r) * 8 + (l4 & 7)] =
            (_Float16)Sf[c][r];

    // ---- rescale O and l, then O += P@V and l += P@ones (MFMA rowsum) ----
#pragma unroll
    for (int c = 0; c < 8; c++) {
      Oacc[c][0] *= alpha[0]; Oacc[c][1] *= alpha[1];
      Oacc[c][2] *= alpha[2]; Oacc[c][3] *= alpha[3];
    }
    lacc[0] *= alpha[0]; lacc[1] *= alpha[1];
    lacc[2] *= alpha[2]; lacc[3] *= alpha[3];
#pragma unroll
    for (int t = 0; t < 2; t++) {
      half8 ap = *(const half8*)&lds.kv.p[wave][((t * 4 + quad) * 16 + l4) * 8];
      lacc = __builtin_amdgcn_mfma_f32_16x16x32_f16(ap, vones, lacc, 0, 0, 0);
#pragma unroll
      for (int c = 0; c < 8; c++) {
        half8 bv = *(const half8*)&lds.kv.v[c][t][l4][quad][0];
        Oacc[c] = __builtin_amdgcn_mfma_f32_16x16x32_f16(ap, bv, Oacc[c], 0, 0, 0);
      }
    }
    __syncthreads();  // b2: all reads done -> safe to restage
  }

  // ---- epilogue: store unnormalized partial O (fp16) + per-row (m, l) ----
  {
    const int rbase = wave * 16 + quad * 4;
    const size_t rowbase = (size_t)(s * NHEAD + h) * NROWS + q0 + rbase;
#pragma unroll
    for (int c = 0; c < 8; c++) {
      const int col = c * 16 + l4;
#pragma unroll
      for (int r = 0; r < 4; r++)
        op[(rowbase + r) * DDIM + col] = (_Float16)Oacc[c][r];
    }
    if (l4 == 0) {
#pragma unroll
      for (int r = 0; r < 4; r++) {
        mb[rowbase + r] = m_run[r];
        lb[rowbase + r] = lacc[r];
      }
    }
  }
}

// ---------------------------------------------------------------------------
// Kernel 3: merge split-K partials + head-sum: u[n][d] =
//   sum_h Wm[h] * (O1*e^{m1-m} + O2*e^{m2-m}) / (l1*e^{m1-m} + l2*e^{m2-m}).
// grid 4096 (one row), block 128 (one d each).
// ---------------------------------------------------------------------------
__global__ __launch_bounds__(128) void merge_kernel(
    const _Float16* __restrict__ op, const float* __restrict__ mb,
    const float* __restrict__ lb, const float* __restrict__ Wm,
    float* __restrict__ u)
{
  __shared__ float sc[2][NHEAD];
  const int n = blockIdx.x, d = threadIdx.x;
  if (d < NHEAD) {
    const int h = d;
    const float m1 = mb[(size_t)h * NROWS + n];
    const float m2 = mb[(size_t)(NHEAD + h) * NROWS + n];
    const float l1 = lb[(size_t)h * NROWS + n];
    const float l2 = lb[(size_t)(NHEAD + h) * NROWS + n];
    const float m  = fmaxf(m1, m2);
    const float a1 = __expf(m1 - m), a2 = __expf(m2 - m);
    const float invL = Wm[h] / (l1 * a1 + l2 * a2);
    sc[0][h] = a1 * invL;
    sc[1][h] = a2 * invL;
  }
  __syncthreads();
  float acc = 0.f;
#pragma unroll
  for (int h = 0; h < NHEAD; h++) {
    acc += sc[0][h] * (float)op[((size_t)h * NROWS + n) * DDIM + d];
    acc += sc[1][h] * (float)op[((size_t)(NHEAD + h) * NROWS + n) * DDIM + d];
  }
  u[(size_t)n * DDIM + d] = acc;
}

// ---------------------------------------------------------------------------
// Kernel 4: y = x + relu((x+u) @ Wg^T + bg), fp32 VALU. grid 2048 x 256.
// ---------------------------------------------------------------------------
__global__ __launch_bounds__(256) void mlp_kernel(
    const float* __restrict__ x, const float* __restrict__ u,
    const float* __restrict__ Wg, const float* __restrict__ bg,
    float* __restrict__ out)
{
  __shared__ float h_s[2][DDIM];
  const int t = threadIdx.x, i = t & 127, r = t >> 7;
  const int n = blockIdx.x * 2 + r;
  h_s[r][i] = x[(size_t)n * DDIM + i] + u[(size_t)n * DDIM + i];
  __syncthreads();
  float g = 0.f;
  for (int j = 0; j < DDIM; j++)
    g += h_s[r][j] * Wg[i * DDIM + j];
  out[(size_t)n * DDIM + i] = x[(size_t)n * DDIM + i] + fmaxf(g + bg[i], 0.f);
}

extern "C" void kernel_launch(void* const* d_in, const int* in_sizes, int n_in,
                              void* d_out, int out_size, void* d_ws, size_t ws_size,
                              hipStream_t stream) {
  float* out = (float*)d_out;
  const int fill_blocks = (out_size + 255) / 256;

  const bool ok_sizes =
      n_in == 7 &&
      in_sizes[0] == NROWS * DDIM &&
      in_sizes[1] == NHEAD * DDIM * DDIM &&
      in_sizes[2] == NHEAD * DDIM * DDIM &&
      in_sizes[3] == NHEAD * DDIM * DDIM &&
      in_sizes[4] == NHEAD &&
      in_sizes[5] == DDIM * DDIM &&
      in_sizes[6] == DDIM &&
      out_size == NROWS * DDIM;
  if (!ok_sizes) {
    fill_kernel<<<fill_blocks, 256, 0, stream>>>(out, 1000.f, out_size);
    return;
  }

  // ws: u 2MB + kh 8.4 + vt 8.4 + op 16.8 + mb/lb 0.5 = 36.6MB
  // (>= 50.3MB demonstrated working in rounds 1-3)
  const size_t HND = (size_t)NHEAD * NROWS * DDIM;
  const size_t ND  = (size_t)NROWS * DDIM;
  const size_t need = ND * 4 + 2 * HND * 2 + 2 * HND * 2 + 2 * NHEAD * NROWS * 8;
  if (ws_size < need) {
    fill_kernel<<<fill_blocks, 256, 0, stream>>>(out, 500.f, out_size);
    return;
  }

  const float* x  = (const float*)d_in[0];
  const float* Wk = (const float*)d_in[1];
  const float* Wq = (const float*)d_in[2];
  const float* Wv = (const float*)d_in[3];
  const float* Wm = (const float*)d_in[4];
  const float* Wg = (const float*)d_in[5];
  const float* bg = (const float*)d_in[6];

  float*     u  = (float*)d_ws;
  _Float16*  kh = (_Float16*)(u + ND);
  _Float16*  vt = kh + HND;
  _Float16*  op = vt + HND;            // 2*HND fp16 partial O
  float*     mb = (float*)(op + 2 * HND);
  float*     lb = mb + 2 * NHEAD * NROWS;

  (void)hipGetLastError();
  proj_kernel<<<dim3(64, NHEAD, 2), 256, 0, stream>>>(x, Wk, Wv, kh, vt);
  flash_kernel<<<dim3(1024), 256, 0, stream>>>(x, Wq, kh, vt, op, mb, lb);
  merge_kernel<<<dim3(4096), 128, 0, stream>>>(op, mb, lb, Wm, u);
  mlp_kernel<<<dim3(2048), 256, 0, stream>>>(x, u, Wg, bg, out);
  if (hipGetLastError() != hipSuccess) {
    fill_kernel<<<fill_blocks, 256, 0, stream>>>(out, 2000.f, out_size);
  }
}

// Round 11
// 299.496 us; speedup vs baseline: 2.0719x; 1.0848x over previous
//
#include <hip/hip_runtime.h>

#define NROWS 4096
#define DDIM  128
#define NHEAD 8

typedef __attribute__((ext_vector_type(8))) short    short8;
typedef __attribute__((ext_vector_type(8))) _Float16 half8;
typedef __attribute__((ext_vector_type(4))) float    floatx4;

__device__ __forceinline__ float bf2f(unsigned short u){
  unsigned v = ((unsigned)u) << 16;
  return __builtin_bit_cast(float, v);
}
__device__ __forceinline__ unsigned short f2bf(float f){
  unsigned u = __builtin_bit_cast(unsigned, f);
  u += 0x7FFFu + ((u >> 16) & 1u);
  return (unsigned short)(u >> 16);
}
__device__ __forceinline__ void split2(float v, unsigned short& hi, unsigned short& lo){
  hi = f2bf(v);
  lo = f2bf(v - bf2f(hi));
}
// async global->LDS, 16B per lane: LDS dest = wave-uniform base + lane*16.
__device__ __forceinline__ void async_cp16(const _Float16* g, _Float16* l){
  __builtin_amdgcn_global_load_lds(
      (const __attribute__((address_space(1))) void*)g,
      (__attribute__((address_space(3))) void*)l, 16, 0, 0);
}

// fp32 sentinels: 500=ws too small, 1000=in_sizes mismatch, 2000=launch fail.
__global__ void fill_kernel(float* __restrict__ out, float val, int n){
  int i = blockIdx.x * 256 + threadIdx.x;
  if (i < n) out[i] = val;
}

// ---------------------------------------------------------------------------
// Kernel 1: k = x@Wk[h], v = x@Wv[h]; outputs fp16 in MFMA FRAGMENT ORDER with
// bank swizzle qX = quad ^ ((l4>>1)&3) baked in:
//   kfo[h][kt][c2][t][l4][qX][j]: element (key=kt*64+c2*16+l4, d=t*32+q*8+j)
//   vfo[h][kt][c2][t][l4][qX][j]: element (d=c2*16+l4, key=kt*64+t*32+q*8+j)
// so flash staging is a LINEAR copy and frag reads are conflict-free.
// 3-term bf16 MFMA from fp32 inputs. grid (64, NHEAD, 2), block 256.
// ---------------------------------------------------------------------------
__global__ __launch_bounds__(256, 2) void proj_kernel(
    const float* __restrict__ x,
    const float* __restrict__ Wk, const float* __restrict__ Wv,
    _Float16* __restrict__ kfo, _Float16* __restrict__ vfo)
{
  __shared__ alignas(16) unsigned short wthi[DDIM][72];
  __shared__ alignas(16) unsigned short wtlo[DDIM][72];
  const int tid = threadIdx.x, lane = tid & 63, wave = tid >> 6;
  const int l4 = lane & 15, quad = lane >> 4;
  const int tile = blockIdx.x, h = blockIdx.y, z = blockIdx.z;
  const float* W = (z == 0 ? Wk : Wv) + h * DDIM * DDIM;

  floatx4 acc[8];
#pragma unroll
  for (int c = 0; c < 8; c++) acc[c] = (floatx4)0.f;

  for (int fh = 0; fh < 2; fh++) {
    for (int i = tid; i < DDIM * 64; i += 256) {
      const int d = i >> 6, fl = i & 63;
      unsigned short hi, lo;
      split2(W[(fh * 64 + fl) * DDIM + d], hi, lo);
      wthi[d][fl] = hi; wtlo[d][fl] = lo;
    }
    __syncthreads();

    const float* xr = x + (size_t)(tile * 64 + wave * 16 + l4) * DDIM + fh * 64 + quad * 8;
    short8 ah[2], al[2];
#pragma unroll
    for (int t2 = 0; t2 < 2; t2++) {
      float4 v0 = *(const float4*)(xr + t2 * 32);
      float4 v1 = *(const float4*)(xr + t2 * 32 + 4);
      float xv[8] = {v0.x, v0.y, v0.z, v0.w, v1.x, v1.y, v1.z, v1.w};
#pragma unroll
      for (int j = 0; j < 8; j++) {
        unsigned short hi, lo; split2(xv[j], hi, lo);
        ah[t2][j] = (short)hi; al[t2][j] = (short)lo;
      }
    }
#pragma unroll
    for (int t2 = 0; t2 < 2; t2++) {
#pragma unroll
      for (int c = 0; c < 8; c++) {
        short8 bh = *(const short8*)(&wthi[c * 16 + l4][t2 * 32 + quad * 8]);
        short8 bl = *(const short8*)(&wtlo[c * 16 + l4][t2 * 32 + quad * 8]);
        acc[c] = __builtin_amdgcn_mfma_f32_16x16x32_bf16(ah[t2], bh, acc[c], 0, 0, 0);
        acc[c] = __builtin_amdgcn_mfma_f32_16x16x32_bf16(al[t2], bh, acc[c], 0, 0, 0);
        acc[c] = __builtin_amdgcn_mfma_f32_16x16x32_bf16(ah[t2], bl, acc[c], 0, 0, 0);
      }
    }
    __syncthreads();
  }

  const int rb = wave * 16 + quad * 4;
  const size_t tilebase = (size_t)(h * 64 + tile) * 8192;
#pragma unroll
  for (int c = 0; c < 8; c++) {
    const int d = c * 16 + l4;
#pragma unroll
    for (int r = 0; r < 4; r++) {
      const int kl = rb + r;            // key index within tile
      const float val = acc[c][r];
      if (z == 0) {
        const int c2 = kl >> 4, l4k = kl & 15;
        const int tt = d >> 5, qd = (d >> 3) & 3, jj = d & 7;
        const int qX = qd ^ ((l4k >> 1) & 3);
        kfo[tilebase + (size_t)((c2 * 4 + tt) * 16 + l4k) * 32 + qX * 8 + jj] =
            (_Float16)val;
      } else {
        const int c2 = d >> 4, l4v = d & 15;
        const int tt = kl >> 5, qd = (kl >> 3) & 3, jj = kl & 7;
        const int qX = qd ^ ((l4v >> 1) & 3);
        vfo[tilebase + (size_t)((c2 * 2 + tt) * 16 + l4v) * 32 + qX * 8 + jj] =
            (_Float16)val;
      }
    }
  }
}

// ---------------------------------------------------------------------------
// Kernel 2: flash attention, SPLIT-K x2. grid 1024: h=bid&7 (XCD-affine),
// qt=(bid>>3)&63, s=bid>>9; block covers key tiles [s*32, s*32+32).
// Staging: global_load_lds width-16 linear copy of frag-ordered K/V tiles;
// frag reads bank-conflict-free via the baked qX swizzle.
// l via ones-MFMA. Unnormalized partial O (fp16) + (m,l) to ws; no atomics.
// LDS union = 40960 B -> exactly 4 blocks/CU.
// ---------------------------------------------------------------------------
union FlashLds {
  struct { unsigned short hi[DDIM][72], lo[DDIM][72]; } wq;  // 36864 B
  float qf[64][132];                                         // 33792 B
  struct { _Float16 k[8192], v[8192], p[4][1024]; } kv;      // 40960 B
};

__global__ __launch_bounds__(256, 4) void flash_kernel(
    const float* __restrict__ x, const float* __restrict__ Wq,
    const _Float16* __restrict__ kfo, const _Float16* __restrict__ vfo,
    _Float16* __restrict__ op, float* __restrict__ mb, float* __restrict__ lb)
{
  __shared__ alignas(16) FlashLds lds;
  const int tid = threadIdx.x, lane = tid & 63, wave = tid >> 6;
  const int l4 = lane & 15, quad = lane >> 4;
  const int h = blockIdx.x & 7, qt = (blockIdx.x >> 3) & 63, s = blockIdx.x >> 9;
  const int q0 = qt * 64;

  // ---- phase 1: q = x @ Wq[h] for this block's 64 rows (3-term bf16) ----
  floatx4 qacc[8];
#pragma unroll
  for (int c = 0; c < 8; c++) qacc[c] = (floatx4)0.f;
  {
    const float* Wqh = Wq + h * DDIM * DDIM;
    for (int fh = 0; fh < 2; fh++) {
      for (int i = tid; i < DDIM * 64; i += 256) {
        const int d = i >> 6, fl = i & 63;
        unsigned short hi, lo;
        split2(Wqh[(fh * 64 + fl) * DDIM + d], hi, lo);
        lds.wq.hi[d][fl] = hi; lds.wq.lo[d][fl] = lo;
      }
      __syncthreads();
      const float* xr = x + (size_t)(q0 + wave * 16 + l4) * DDIM + fh * 64 + quad * 8;
      short8 ah[2], al[2];
#pragma unroll
      for (int t2 = 0; t2 < 2; t2++) {
        float4 v0 = *(const float4*)(xr + t2 * 32);
        float4 v1 = *(const float4*)(xr + t2 * 32 + 4);
        float xv[8] = {v0.x, v0.y, v0.z, v0.w, v1.x, v1.y, v1.z, v1.w};
#pragma unroll
        for (int j = 0; j < 8; j++) {
          unsigned short hi, lo; split2(xv[j], hi, lo);
          ah[t2][j] = (short)hi; al[t2][j] = (short)lo;
        }
      }
#pragma unroll
      for (int t2 = 0; t2 < 2; t2++) {
#pragma unroll
        for (int c = 0; c < 8; c++) {
          short8 bh = *(const short8*)(&lds.wq.hi[c * 16 + l4][t2 * 32 + quad * 8]);
          short8 bl = *(const short8*)(&lds.wq.lo[c * 16 + l4][t2 * 32 + quad * 8]);
          qacc[c] = __builtin_amdgcn_mfma_f32_16x16x32_bf16(ah[t2], bh, qacc[c], 0, 0, 0);
          qacc[c] = __builtin_amdgcn_mfma_f32_16x16x32_bf16(al[t2], bh, qacc[c], 0, 0, 0);
          qacc[c] = __builtin_amdgcn_mfma_f32_16x16x32_bf16(ah[t2], bl, qacc[c], 0, 0, 0);
        }
      }
      __syncthreads();
    }
  }
  // q: C-layout -> LDS fp32 -> fp16 A-frags
#pragma unroll
  for (int c = 0; c < 8; c++)
#pragma unroll
    for (int r = 0; r < 4; r++)
      lds.qf[wave * 16 + quad * 4 + r][c * 16 + l4] = qacc[c][r];
  __syncthreads();
  half8 aq[4];
#pragma unroll
  for (int t = 0; t < 4; t++) {
    float4 v0 = *(const float4*)(&lds.qf[wave * 16 + l4][t * 32 + quad * 8]);
    float4 v1 = *(const float4*)(&lds.qf[wave * 16 + l4][t * 32 + quad * 8 + 4]);
    aq[t][0] = (_Float16)v0.x; aq[t][1] = (_Float16)v0.y;
    aq[t][2] = (_Float16)v0.z; aq[t][3] = (_Float16)v0.w;
    aq[t][4] = (_Float16)v1.x; aq[t][5] = (_Float16)v1.y;
    aq[t][6] = (_Float16)v1.z; aq[t][7] = (_Float16)v1.w;
  }
  __syncthreads();  // qf reads done; kv region may now be used

  // ---- kt loop ----
  float m_run[4];
#pragma unroll
  for (int r = 0; r < 4; r++) m_run[r] = -1e30f;
  floatx4 Oacc[8], lacc = (floatx4)0.f;
#pragma unroll
  for (int c = 0; c < 8; c++) Oacc[c] = (floatx4)0.f;

  half8 vones;
#pragma unroll
  for (int j = 0; j < 8; j++) vones[j] = (_Float16)1.f;

  const _Float16* kfo_h = kfo + (size_t)h * 64 * 8192;
  const _Float16* vfo_h = vfo + (size_t)h * 64 * 8192;
  // per-lane fragment offset (swizzle folded in, constant across kt):
  const int lq = (l4 * 4 + (quad ^ ((l4 >> 1) & 3))) * 8;

  for (int kt = s * 32; kt < s * 32 + 32; ++kt) {
    // ---- stage K/V tiles: linear async copy, 4KB per wave each ----
    {
      const _Float16* ks = kfo_h + (size_t)kt * 8192 + wave * 2048 + lane * 8;
      const _Float16* vs = vfo_h + (size_t)kt * 8192 + wave * 2048 + lane * 8;
      _Float16* kd = &lds.kv.k[wave * 2048];
      _Float16* vd = &lds.kv.v[wave * 2048];
#pragma unroll
      for (int it = 0; it < 4; it++) {
        async_cp16(ks + it * 512, kd + it * 512);
        async_cp16(vs + it * 512, vd + it * 512);
      }
    }
    __syncthreads();  // b1: drains vmcnt, tiles staged

    // ---- S = Q @ K^T ----
    floatx4 Sf[4];
#pragma unroll
    for (int c = 0; c < 4; c++) Sf[c] = (floatx4)0.f;
#pragma unroll
    for (int t = 0; t < 4; t++) {
      half8 b[4];
#pragma unroll
      for (int c = 0; c < 4; c++)
        b[c] = *(const half8*)&lds.kv.k[(c * 4 + t) * 512 + lq];
#pragma unroll
      for (int c = 0; c < 4; c++)
        Sf[c] = __builtin_amdgcn_mfma_f32_16x16x32_f16(aq[t], b[c], Sf[c], 0, 0, 0);
    }

    // ---- per-wave register softmax: tile max + alpha ----
    float mt[4];
#pragma unroll
    for (int r = 0; r < 4; r++)
      mt[r] = fmaxf(fmaxf(Sf[0][r], Sf[1][r]), fmaxf(Sf[2][r], Sf[3][r]));
#pragma unroll
    for (int mk = 1; mk <= 8; mk <<= 1)
#pragma unroll
      for (int r = 0; r < 4; r++) mt[r] = fmaxf(mt[r], __shfl_xor(mt[r], mk, 64));

    float alpha[4];
#pragma unroll
    for (int r = 0; r < 4; r++) {
      const float mn = fmaxf(m_run[r], mt[r]);
      alpha[r] = __expf(m_run[r] - mn);
      m_run[r] = mn;
    }
#pragma unroll
    for (int r = 0; r < 4; r++)
#pragma unroll
      for (int c = 0; c < 4; c++) Sf[c][r] = __expf(Sf[c][r] - m_run[r]);

    // ---- P: C-layout -> A-layout, wave-private LDS ----
#pragma unroll
    for (int c = 0; c < 4; c++)
#pragma unroll
      for (int r = 0; r < 4; r++)
        lds.kv.p[wave][((c * 2 + (l4 >> 3)) * 16 + quad * 4 + r) * 8 + (l4 & 7)] =
            (_Float16)Sf[c][r];

    // ---- rescale O/l, then O += P@V, l += P@ones ----
#pragma unroll
    for (int c = 0; c < 8; c++) {
      Oacc[c][0] *= alpha[0]; Oacc[c][1] *= alpha[1];
      Oacc[c][2] *= alpha[2]; Oacc[c][3] *= alpha[3];
    }
    lacc[0] *= alpha[0]; lacc[1] *= alpha[1];
    lacc[2] *= alpha[2]; lacc[3] *= alpha[3];
#pragma unroll
    for (int t = 0; t < 2; t++) {
      half8 ap = *(const half8*)&lds.kv.p[wave][((t * 4 + quad) * 16 + l4) * 8];
      lacc = __builtin_amdgcn_mfma_f32_16x16x32_f16(ap, vones, lacc, 0, 0, 0);
#pragma unroll
      for (int c = 0; c < 8; c++) {
        half8 bv = *(const half8*)&lds.kv.v[(c * 2 + t) * 512 + lq];
        Oacc[c] = __builtin_amdgcn_mfma_f32_16x16x32_f16(ap, bv, Oacc[c], 0, 0, 0);
      }
    }
    __syncthreads();  // b2: all reads done -> safe to restage
  }

  // ---- epilogue: unnormalized partial O (fp16) + per-row (m, l) ----
  {
    const int rbase = wave * 16 + quad * 4;
    const size_t rowbase = (size_t)(s * NHEAD + h) * NROWS + q0 + rbase;
#pragma unroll
    for (int c = 0; c < 8; c++) {
      const int col = c * 16 + l4;
#pragma unroll
      for (int r = 0; r < 4; r++)
        op[(rowbase + r) * DDIM + col] = (_Float16)Oacc[c][r];
    }
    if (l4 == 0) {
#pragma unroll
      for (int r = 0; r < 4; r++) {
        mb[rowbase + r] = m_run[r];
        lb[rowbase + r] = lacc[r];
      }
    }
  }
}

// ---------------------------------------------------------------------------
// Kernel 3: merge split-K partials + head-sum -> u. grid 4096, block 128.
// ---------------------------------------------------------------------------
__global__ __launch_bounds__(128) void merge_kernel(
    const _Float16* __restrict__ op, const float* __restrict__ mb,
    const float* __restrict__ lb, const float* __restrict__ Wm,
    float* __restrict__ u)
{
  __shared__ float sc[2][NHEAD];
  const int n = blockIdx.x, d = threadIdx.x;
  if (d < NHEAD) {
    const int h = d;
    const float m1 = mb[(size_t)h * NROWS + n];
    const float m2 = mb[(size_t)(NHEAD + h) * NROWS + n];
    const float l1 = lb[(size_t)h * NROWS + n];
    const float l2 = lb[(size_t)(NHEAD + h) * NROWS + n];
    const float m  = fmaxf(m1, m2);
    const float a1 = __expf(m1 - m), a2 = __expf(m2 - m);
    const float invL = Wm[h] / (l1 * a1 + l2 * a2);
    sc[0][h] = a1 * invL;
    sc[1][h] = a2 * invL;
  }
  __syncthreads();
  float acc = 0.f;
#pragma unroll
  for (int h = 0; h < NHEAD; h++) {
    acc += sc[0][h] * (float)op[((size_t)h * NROWS + n) * DDIM + d];
    acc += sc[1][h] * (float)op[((size_t)(NHEAD + h) * NROWS + n) * DDIM + d];
  }
  u[(size_t)n * DDIM + d] = acc;
}

// ---------------------------------------------------------------------------
// Kernel 4: y = x + relu((x+u) @ Wg^T + bg), fp32 VALU. grid 2048 x 256.
// ---------------------------------------------------------------------------
__global__ __launch_bounds__(256) void mlp_kernel(
    const float* __restrict__ x, const float* __restrict__ u,
    const float* __restrict__ Wg, const float* __restrict__ bg,
    float* __restrict__ out)
{
  __shared__ float h_s[2][DDIM];
  const int t = threadIdx.x, i = t & 127, r = t >> 7;
  const int n = blockIdx.x * 2 + r;
  h_s[r][i] = x[(size_t)n * DDIM + i] + u[(size_t)n * DDIM + i];
  __syncthreads();
  float g = 0.f;
  for (int j = 0; j < DDIM; j++)
    g += h_s[r][j] * Wg[i * DDIM + j];
  out[(size_t)n * DDIM + i] = x[(size_t)n * DDIM + i] + fmaxf(g + bg[i], 0.f);
}

extern "C" void kernel_launch(void* const* d_in, const int* in_sizes, int n_in,
                              void* d_out, int out_size, void* d_ws, size_t ws_size,
                              hipStream_t stream) {
  float* out = (float*)d_out;
  const int fill_blocks = (out_size + 255) / 256;

  const bool ok_sizes =
      n_in == 7 &&
      in_sizes[0] == NROWS * DDIM &&
      in_sizes[1] == NHEAD * DDIM * DDIM &&
      in_sizes[2] == NHEAD * DDIM * DDIM &&
      in_sizes[3] == NHEAD * DDIM * DDIM &&
      in_sizes[4] == NHEAD &&
      in_sizes[5] == DDIM * DDIM &&
      in_sizes[6] == DDIM &&
      out_size == NROWS * DDIM;
  if (!ok_sizes) {
    fill_kernel<<<fill_blocks, 256, 0, stream>>>(out, 1000.f, out_size);
    return;
  }

  // ws: u 2MB + kfo 8.4 + vfo 8.4 + op 16.8 + mb/lb 0.5 = 36.6MB
  const size_t HND = (size_t)NHEAD * NROWS * DDIM;
  const size_t ND  = (size_t)NROWS * DDIM;
  const size_t need = ND * 4 + 2 * HND * 2 + 2 * HND * 2 + 2 * NHEAD * NROWS * 8;
  if (ws_size < need) {
    fill_kernel<<<fill_blocks, 256, 0, stream>>>(out, 500.f, out_size);
    return;
  }

  const float* x  = (const float*)d_in[0];
  const float* Wk = (const float*)d_in[1];
  const float* Wq = (const float*)d_in[2];
  const float* Wv = (const float*)d_in[3];
  const float* Wm = (const float*)d_in[4];
  const float* Wg = (const float*)d_in[5];
  const float* bg = (const float*)d_in[6];

  float*     u   = (float*)d_ws;
  _Float16*  kfo = (_Float16*)(u + ND);
  _Float16*  vfo = kfo + HND;
  _Float16*  op  = vfo + HND;
  float*     mb  = (float*)(op + 2 * HND);
  float*     lb  = mb + 2 * NHEAD * NROWS;

  (void)hipGetLastError();
  proj_kernel<<<dim3(64, NHEAD, 2), 256, 0, stream>>>(x, Wk, Wv, kfo, vfo);
  flash_kernel<<<dim3(1024), 256, 0, stream>>>(x, Wq, kfo, vfo, op, mb, lb);
  merge_kernel<<<dim3(4096), 128, 0, stream>>>(op, mb, lb, Wm, u);
  mlp_kernel<<<dim3(2048), 256, 0, stream>>>(x, u, Wg, bg, out);
  if (hipGetLastError() != hipSuccess) {
    fill_kernel<<<fill_blocks, 256, 0, stream>>>(out, 2000.f, out_size);
  }
}

// Round 12
// 261.396 us; speedup vs baseline: 2.3738x; 1.1458x over previous
//
#include <hip/hip_runtime.h>

#define NROWS 4096
#define DDIM  128
#define NHEAD 8

typedef __attribute__((ext_vector_type(8))) short    short8;
typedef __attribute__((ext_vector_type(8))) _Float16 half8;
typedef __attribute__((ext_vector_type(4))) float    floatx4;

__device__ __forceinline__ float bf2f(unsigned short u){
  unsigned v = ((unsigned)u) << 16;
  return __builtin_bit_cast(float, v);
}
__device__ __forceinline__ unsigned short f2bf(float f){
  unsigned u = __builtin_bit_cast(unsigned, f);
  u += 0x7FFFu + ((u >> 16) & 1u);
  return (unsigned short)(u >> 16);
}
__device__ __forceinline__ void split2(float v, unsigned short& hi, unsigned short& lo){
  hi = f2bf(v);
  lo = f2bf(v - bf2f(hi));
}
// async global->LDS, 16B per lane: LDS dest = wave-uniform base + lane*16.
__device__ __forceinline__ void async_cp16(const _Float16* g, _Float16* l){
  __builtin_amdgcn_global_load_lds(
      (const __attribute__((address_space(1))) void*)g,
      (__attribute__((address_space(3))) void*)l, 16, 0, 0);
}

// fp32 sentinels: 500=ws too small, 1000=in_sizes mismatch, 2000=launch fail.
__global__ void fill_kernel(float* __restrict__ out, float val, int n){
  int i = blockIdx.x * 256 + threadIdx.x;
  if (i < n) out[i] = val;
}

// ---------------------------------------------------------------------------
// Kernel 1: k = x@Wk[h], v = x@Wv[h]; fp16 outputs in MFMA fragment order
// with bank swizzle qX = quad ^ ((l4>>1)&3) baked in (see R10 notes).
// 3-term bf16 MFMA from fp32 inputs. grid (64, NHEAD, 2), block 256.
// ---------------------------------------------------------------------------
__global__ __launch_bounds__(256, 2) void proj_kernel(
    const float* __restrict__ x,
    const float* __restrict__ Wk, const float* __restrict__ Wv,
    _Float16* __restrict__ kfo, _Float16* __restrict__ vfo)
{
  __shared__ alignas(16) unsigned short wthi[DDIM][72];
  __shared__ alignas(16) unsigned short wtlo[DDIM][72];
  const int tid = threadIdx.x, lane = tid & 63, wave = tid >> 6;
  const int l4 = lane & 15, quad = lane >> 4;
  const int tile = blockIdx.x, h = blockIdx.y, z = blockIdx.z;
  const float* W = (z == 0 ? Wk : Wv) + h * DDIM * DDIM;

  floatx4 acc[8];
#pragma unroll
  for (int c = 0; c < 8; c++) acc[c] = (floatx4)0.f;

  for (int fh = 0; fh < 2; fh++) {
    for (int i = tid; i < DDIM * 64; i += 256) {
      const int d = i >> 6, fl = i & 63;
      unsigned short hi, lo;
      split2(W[(fh * 64 + fl) * DDIM + d], hi, lo);
      wthi[d][fl] = hi; wtlo[d][fl] = lo;
    }
    __syncthreads();

    const float* xr = x + (size_t)(tile * 64 + wave * 16 + l4) * DDIM + fh * 64 + quad * 8;
    short8 ah[2], al[2];
#pragma unroll
    for (int t2 = 0; t2 < 2; t2++) {
      float4 v0 = *(const float4*)(xr + t2 * 32);
      float4 v1 = *(const float4*)(xr + t2 * 32 + 4);
      float xv[8] = {v0.x, v0.y, v0.z, v0.w, v1.x, v1.y, v1.z, v1.w};
#pragma unroll
      for (int j = 0; j < 8; j++) {
        unsigned short hi, lo; split2(xv[j], hi, lo);
        ah[t2][j] = (short)hi; al[t2][j] = (short)lo;
      }
    }
#pragma unroll
    for (int t2 = 0; t2 < 2; t2++) {
#pragma unroll
      for (int c = 0; c < 8; c++) {
        short8 bh = *(const short8*)(&wthi[c * 16 + l4][t2 * 32 + quad * 8]);
        short8 bl = *(const short8*)(&wtlo[c * 16 + l4][t2 * 32 + quad * 8]);
        acc[c] = __builtin_amdgcn_mfma_f32_16x16x32_bf16(ah[t2], bh, acc[c], 0, 0, 0);
        acc[c] = __builtin_amdgcn_mfma_f32_16x16x32_bf16(al[t2], bh, acc[c], 0, 0, 0);
        acc[c] = __builtin_amdgcn_mfma_f32_16x16x32_bf16(ah[t2], bl, acc[c], 0, 0, 0);
      }
    }
    __syncthreads();
  }

  const int rb = wave * 16 + quad * 4;
  const size_t tilebase = (size_t)(h * 64 + tile) * 8192;
#pragma unroll
  for (int c = 0; c < 8; c++) {
    const int d = c * 16 + l4;
#pragma unroll
    for (int r = 0; r < 4; r++) {
      const int kl = rb + r;
      const float val = acc[c][r];
      if (z == 0) {
        const int c2 = kl >> 4, l4k = kl & 15;
        const int tt = d >> 5, qd = (d >> 3) & 3, jj = d & 7;
        const int qX = qd ^ ((l4k >> 1) & 3);
        kfo[tilebase + (size_t)((c2 * 4 + tt) * 16 + l4k) * 32 + qX * 8 + jj] =
            (_Float16)val;
      } else {
        const int c2 = d >> 4, l4v = d & 15;
        const int tt = kl >> 5, qd = (kl >> 3) & 3, jj = kl & 7;
        const int qX = qd ^ ((l4v >> 1) & 3);
        vfo[tilebase + (size_t)((c2 * 2 + tt) * 16 + l4v) * 32 + qX * 8 + jj] =
            (_Float16)val;
      }
    }
  }
}

// ---------------------------------------------------------------------------
// Kernel 2: flash attention, 128 q-rows/block, SPLIT-K x2. grid 512:
// h=bid&7 (XCD-affine), qt=(bid>>3)&31 (128-row tiles), s=bid>>8.
// Each wave owns 32 q-rows as 2x16-row groups (g): the 16 K B-frag reads and
// 16 V B-frag reads per iter serve BOTH groups -> per-row LDS traffic halved.
// Phase 1 computes q in two 64-row sub-phases through a 33KB qf buffer.
// All MFMAs are the verified 16x16x32 layouts. LDS = 49152 B.
// ---------------------------------------------------------------------------
union FlashLds {
  struct { unsigned short hi[DDIM][72], lo[DDIM][72]; } wq;  // 36864 B
  float qf[64][132];                                         // 33792 B
  struct { _Float16 k[8192], v[8192], p[4][2][1024]; } kv;   // 49152 B
};

__global__ __launch_bounds__(256, 2) void flash_kernel(
    const float* __restrict__ x, const float* __restrict__ Wq,
    const _Float16* __restrict__ kfo, const _Float16* __restrict__ vfo,
    _Float16* __restrict__ op, float* __restrict__ mb, float* __restrict__ lb)
{
  __shared__ alignas(16) FlashLds lds;
  const int tid = threadIdx.x, lane = tid & 63, wave = tid >> 6;
  const int l4 = lane & 15, quad = lane >> 4;
  const int h = blockIdx.x & 7, qt = (blockIdx.x >> 3) & 31, s = blockIdx.x >> 8;
  const int q0 = qt * 128;

  half8 aq[2][4];  // [row-group g][t] fp16 A-frags, filled in phase 1

  // ---- phase 1: q = x @ Wq[h] for 128 rows, two 64-row sub-phases ----
  {
    floatx4 qacc[2][8];
#pragma unroll
    for (int sp = 0; sp < 2; sp++)
#pragma unroll
      for (int c = 0; c < 8; c++) qacc[sp][c] = (floatx4)0.f;

    const float* Wqh = Wq + h * DDIM * DDIM;
    for (int fh = 0; fh < 2; fh++) {
      for (int i = tid; i < DDIM * 64; i += 256) {
        const int d = i >> 6, fl = i & 63;
        unsigned short hi, lo;
        split2(Wqh[(fh * 64 + fl) * DDIM + d], hi, lo);
        lds.wq.hi[d][fl] = hi; lds.wq.lo[d][fl] = lo;
      }
      __syncthreads();
#pragma unroll
      for (int sp = 0; sp < 2; sp++) {
        const float* xr = x + (size_t)(q0 + sp * 64 + wave * 16 + l4) * DDIM + fh * 64 + quad * 8;
        short8 ah[2], al[2];
#pragma unroll
        for (int t2 = 0; t2 < 2; t2++) {
          float4 v0 = *(const float4*)(xr + t2 * 32);
          float4 v1 = *(const float4*)(xr + t2 * 32 + 4);
          float xv[8] = {v0.x, v0.y, v0.z, v0.w, v1.x, v1.y, v1.z, v1.w};
#pragma unroll
          for (int j = 0; j < 8; j++) {
            unsigned short hi, lo; split2(xv[j], hi, lo);
            ah[t2][j] = (short)hi; al[t2][j] = (short)lo;
          }
        }
#pragma unroll
        for (int t2 = 0; t2 < 2; t2++) {
#pragma unroll
          for (int c = 0; c < 8; c++) {
            short8 bh = *(const short8*)(&lds.wq.hi[c * 16 + l4][t2 * 32 + quad * 8]);
            short8 bl = *(const short8*)(&lds.wq.lo[c * 16 + l4][t2 * 32 + quad * 8]);
            qacc[sp][c] = __builtin_amdgcn_mfma_f32_16x16x32_bf16(ah[t2], bh, qacc[sp][c], 0, 0, 0);
            qacc[sp][c] = __builtin_amdgcn_mfma_f32_16x16x32_bf16(al[t2], bh, qacc[sp][c], 0, 0, 0);
            qacc[sp][c] = __builtin_amdgcn_mfma_f32_16x16x32_bf16(ah[t2], bl, qacc[sp][c], 0, 0, 0);
          }
        }
      }
      __syncthreads();
    }

    // round-trip each 64-row half through qf; owning waves extract fp16 A-frags
#pragma unroll
    for (int sp = 0; sp < 2; sp++) {
#pragma unroll
      for (int c = 0; c < 8; c++)
#pragma unroll
        for (int r = 0; r < 4; r++)
          lds.qf[wave * 16 + quad * 4 + r][c * 16 + l4] = qacc[sp][c][r];
      __syncthreads();
      if ((wave >> 1) == sp) {
#pragma unroll
        for (int g = 0; g < 2; g++)
#pragma unroll
          for (int t = 0; t < 4; t++) {
            const float* qr = &lds.qf[(wave & 1) * 32 + g * 16 + l4][t * 32 + quad * 8];
            float4 v0 = *(const float4*)qr;
            float4 v1 = *(const float4*)(qr + 4);
            aq[g][t][0] = (_Float16)v0.x; aq[g][t][1] = (_Float16)v0.y;
            aq[g][t][2] = (_Float16)v0.z; aq[g][t][3] = (_Float16)v0.w;
            aq[g][t][4] = (_Float16)v1.x; aq[g][t][5] = (_Float16)v1.y;
            aq[g][t][6] = (_Float16)v1.z; aq[g][t][7] = (_Float16)v1.w;
          }
      }
      __syncthreads();
    }
  }

  // ---- kt loop ----
  float m_run[2][4];
#pragma unroll
  for (int g = 0; g < 2; g++)
#pragma unroll
    for (int r = 0; r < 4; r++) m_run[g][r] = -1e30f;
  floatx4 Oacc[2][8], lacc[2];
#pragma unroll
  for (int g = 0; g < 2; g++) {
    lacc[g] = (floatx4)0.f;
#pragma unroll
    for (int c = 0; c < 8; c++) Oacc[g][c] = (floatx4)0.f;
  }

  half8 vones;
#pragma unroll
  for (int j = 0; j < 8; j++) vones[j] = (_Float16)1.f;

  const _Float16* kfo_h = kfo + (size_t)h * 64 * 8192;
  const _Float16* vfo_h = vfo + (size_t)h * 64 * 8192;
  const int lq = (l4 * 4 + (quad ^ ((l4 >> 1) & 3))) * 8;

  for (int kt = s * 32; kt < s * 32 + 32; ++kt) {
    // ---- stage K/V tiles: linear async copy, 4KB per wave each ----
    {
      const _Float16* ks = kfo_h + (size_t)kt * 8192 + wave * 2048 + lane * 8;
      const _Float16* vs = vfo_h + (size_t)kt * 8192 + wave * 2048 + lane * 8;
      _Float16* kd = &lds.kv.k[wave * 2048];
      _Float16* vd = &lds.kv.v[wave * 2048];
#pragma unroll
      for (int it = 0; it < 4; it++) {
        async_cp16(ks + it * 512, kd + it * 512);
        async_cp16(vs + it * 512, vd + it * 512);
      }
    }
    __syncthreads();  // b1: tiles staged

    // ---- S = Q @ K^T : 16 K-frag reads serve both row groups ----
    floatx4 Sf[2][4];
#pragma unroll
    for (int g = 0; g < 2; g++)
#pragma unroll
      for (int c = 0; c < 4; c++) Sf[g][c] = (floatx4)0.f;
#pragma unroll
    for (int t = 0; t < 4; t++) {
      half8 b[4];
#pragma unroll
      for (int c = 0; c < 4; c++)
        b[c] = *(const half8*)&lds.kv.k[(c * 4 + t) * 512 + lq];
#pragma unroll
      for (int g = 0; g < 2; g++)
#pragma unroll
        for (int c = 0; c < 4; c++)
          Sf[g][c] = __builtin_amdgcn_mfma_f32_16x16x32_f16(aq[g][t], b[c], Sf[g][c], 0, 0, 0);
    }

    // ---- per-wave register softmax per row group ----
    float alpha[2][4];
#pragma unroll
    for (int g = 0; g < 2; g++) {
      float mt[4];
#pragma unroll
      for (int r = 0; r < 4; r++)
        mt[r] = fmaxf(fmaxf(Sf[g][0][r], Sf[g][1][r]), fmaxf(Sf[g][2][r], Sf[g][3][r]));
#pragma unroll
      for (int mk = 1; mk <= 8; mk <<= 1)
#pragma unroll
        for (int r = 0; r < 4; r++) mt[r] = fmaxf(mt[r], __shfl_xor(mt[r], mk, 64));
#pragma unroll
      for (int r = 0; r < 4; r++) {
        const float mn = fmaxf(m_run[g][r], mt[r]);
        alpha[g][r] = __expf(m_run[g][r] - mn);
        m_run[g][r] = mn;
      }
#pragma unroll
      for (int r = 0; r < 4; r++)
#pragma unroll
        for (int c = 0; c < 4; c++) Sf[g][c][r] = __expf(Sf[g][c][r] - m_run[g][r]);
    }

    // ---- P: C-layout -> A-layout, wave-private frag-ordered LDS ----
#pragma unroll
    for (int g = 0; g < 2; g++)
#pragma unroll
      for (int c = 0; c < 4; c++)
#pragma unroll
        for (int r = 0; r < 4; r++)
          lds.kv.p[wave][g][((c * 2 + (l4 >> 3)) * 16 + quad * 4 + r) * 8 + (l4 & 7)] =
              (_Float16)Sf[g][c][r];

    // ---- rescale O/l, then O += P@V, l += P@ones (16 V reads, both groups) ----
#pragma unroll
    for (int g = 0; g < 2; g++) {
#pragma unroll
      for (int c = 0; c < 8; c++) {
        Oacc[g][c][0] *= alpha[g][0]; Oacc[g][c][1] *= alpha[g][1];
        Oacc[g][c][2] *= alpha[g][2]; Oacc[g][c][3] *= alpha[g][3];
      }
      lacc[g][0] *= alpha[g][0]; lacc[g][1] *= alpha[g][1];
      lacc[g][2] *= alpha[g][2]; lacc[g][3] *= alpha[g][3];
    }
#pragma unroll
    for (int t = 0; t < 2; t++) {
      half8 ap[2];
#pragma unroll
      for (int g = 0; g < 2; g++) {
        ap[g] = *(const half8*)&lds.kv.p[wave][g][((t * 4 + quad) * 16 + l4) * 8];
        lacc[g] = __builtin_amdgcn_mfma_f32_16x16x32_f16(ap[g], vones, lacc[g], 0, 0, 0);
      }
#pragma unroll
      for (int c = 0; c < 8; c++) {
        half8 bv = *(const half8*)&lds.kv.v[(c * 2 + t) * 512 + lq];
#pragma unroll
        for (int g = 0; g < 2; g++)
          Oacc[g][c] = __builtin_amdgcn_mfma_f32_16x16x32_f16(ap[g], bv, Oacc[g][c], 0, 0, 0);
      }
    }
    __syncthreads();  // b2: all reads done -> safe to restage
  }

  // ---- epilogue: unnormalized partial O (fp16) + per-row (m, l) ----
#pragma unroll
  for (int g = 0; g < 2; g++) {
    const int rbase = wave * 32 + g * 16 + quad * 4;
    const size_t rowbase = (size_t)(s * NHEAD + h) * NROWS + q0 + rbase;
#pragma unroll
    for (int c = 0; c < 8; c++) {
      const int col = c * 16 + l4;
#pragma unroll
      for (int r = 0; r < 4; r++)
        op[(rowbase + r) * DDIM + col] = (_Float16)Oacc[g][c][r];
    }
    if (l4 == 0) {
#pragma unroll
      for (int r = 0; r < 4; r++) {
        mb[rowbase + r] = m_run[g][r];
        lb[rowbase + r] = lacc[g][r];
      }
    }
  }
}

// ---------------------------------------------------------------------------
// Kernel 3: merge split-K partials + head-sum -> u. grid 4096, block 128.
// ---------------------------------------------------------------------------
__global__ __launch_bounds__(128) void merge_kernel(
    const _Float16* __restrict__ op, const float* __restrict__ mb,
    const float* __restrict__ lb, const float* __restrict__ Wm,
    float* __restrict__ u)
{
  __shared__ float sc[2][NHEAD];
  const int n = blockIdx.x, d = threadIdx.x;
  if (d < NHEAD) {
    const int h = d;
    const float m1 = mb[(size_t)h * NROWS + n];
    const float m2 = mb[(size_t)(NHEAD + h) * NROWS + n];
    const float l1 = lb[(size_t)h * NROWS + n];
    const float l2 = lb[(size_t)(NHEAD + h) * NROWS + n];
    const float m  = fmaxf(m1, m2);
    const float a1 = __expf(m1 - m), a2 = __expf(m2 - m);
    const float invL = Wm[h] / (l1 * a1 + l2 * a2);
    sc[0][h] = a1 * invL;
    sc[1][h] = a2 * invL;
  }
  __syncthreads();
  float acc = 0.f;
#pragma unroll
  for (int h = 0; h < NHEAD; h++) {
    acc += sc[0][h] * (float)op[((size_t)h * NROWS + n) * DDIM + d];
    acc += sc[1][h] * (float)op[((size_t)(NHEAD + h) * NROWS + n) * DDIM + d];
  }
  u[(size_t)n * DDIM + d] = acc;
}

// ---------------------------------------------------------------------------
// Kernel 4: y = x + relu((x+u) @ Wg^T + bg) via 3-term bf16 MFMA with
// LDS-staged Wg (fixes the uncoalesced Wg[i*128+j] scalar reads).
// grid 64 (64-row tiles), block 256.
// ---------------------------------------------------------------------------
__global__ __launch_bounds__(256, 2) void mlp_kernel(
    const float* __restrict__ x, const float* __restrict__ u,
    const float* __restrict__ Wg, const float* __restrict__ bg,
    float* __restrict__ out)
{
  __shared__ alignas(16) unsigned short wghi[DDIM][72];
  __shared__ alignas(16) unsigned short wglo[DDIM][72];
  const int tid = threadIdx.x, lane = tid & 63, wave = tid >> 6;
  const int l4 = lane & 15, quad = lane >> 4;
  const int r0 = blockIdx.x * 64;

  floatx4 acc[8];
#pragma unroll
  for (int c = 0; c < 8; c++) acc[c] = (floatx4)0.f;

  for (int fh = 0; fh < 2; fh++) {
    // stage Wg chunk: B[l4=i][k=j] = Wg[i][fh*64+j] (row-major direct), hi/lo
    for (int i = tid; i < DDIM * 64; i += 256) {
      const int ii = i >> 6, jl = i & 63;
      unsigned short hi, lo;
      split2(Wg[ii * DDIM + fh * 64 + jl], hi, lo);
      wghi[ii][jl] = hi; wglo[ii][jl] = lo;
    }
    __syncthreads();

    // A-frags: h = x + u for row r0 + wave*16 + l4, cols fh*64 + ...
    const size_t xoff = (size_t)(r0 + wave * 16 + l4) * DDIM + fh * 64 + quad * 8;
    short8 ah[2], al[2];
#pragma unroll
    for (int t2 = 0; t2 < 2; t2++) {
      float4 x0 = *(const float4*)(x + xoff + t2 * 32);
      float4 x1 = *(const float4*)(x + xoff + t2 * 32 + 4);
      float4 u0 = *(const float4*)(u + xoff + t2 * 32);
      float4 u1 = *(const float4*)(u + xoff + t2 * 32 + 4);
      float hv[8] = {x0.x + u0.x, x0.y + u0.y, x0.z + u0.z, x0.w + u0.w,
                     x1.x + u1.x, x1.y + u1.y, x1.z + u1.z, x1.w + u1.w};
#pragma unroll
      for (int j = 0; j < 8; j++) {
        unsigned short hi, lo; split2(hv[j], hi, lo);
        ah[t2][j] = (short)hi; al[t2][j] = (short)lo;
      }
    }
#pragma unroll
    for (int t2 = 0; t2 < 2; t2++) {
#pragma unroll
      for (int c = 0; c < 8; c++) {
        short8 bh = *(const short8*)(&wghi[c * 16 + l4][t2 * 32 + quad * 8]);
        short8 bl = *(const short8*)(&wglo[c * 16 + l4][t2 * 32 + quad * 8]);
        acc[c] = __builtin_amdgcn_mfma_f32_16x16x32_bf16(ah[t2], bh, acc[c], 0, 0, 0);
        acc[c] = __builtin_amdgcn_mfma_f32_16x16x32_bf16(al[t2], bh, acc[c], 0, 0, 0);
        acc[c] = __builtin_amdgcn_mfma_f32_16x16x32_bf16(ah[t2], bl, acc[c], 0, 0, 0);
      }
    }
    __syncthreads();
  }

  const int rbase = wave * 16 + quad * 4;
#pragma unroll
  for (int c = 0; c < 8; c++) {
    const int col = c * 16 + l4;
    const float bgf = bg[col];
#pragma unroll
    for (int r = 0; r < 4; r++) {
      const size_t idx = (size_t)(r0 + rbase + r) * DDIM + col;
      out[idx] = x[idx] + fmaxf(acc[c][r] + bgf, 0.f);
    }
  }
}

extern "C" void kernel_launch(void* const* d_in, const int* in_sizes, int n_in,
                              void* d_out, int out_size, void* d_ws, size_t ws_size,
                              hipStream_t stream) {
  float* out = (float*)d_out;
  const int fill_blocks = (out_size + 255) / 256;

  const bool ok_sizes =
      n_in == 7 &&
      in_sizes[0] == NROWS * DDIM &&
      in_sizes[1] == NHEAD * DDIM * DDIM &&
      in_sizes[2] == NHEAD * DDIM * DDIM &&
      in_sizes[3] == NHEAD * DDIM * DDIM &&
      in_sizes[4] == NHEAD &&
      in_sizes[5] == DDIM * DDIM &&
      in_sizes[6] == DDIM &&
      out_size == NROWS * DDIM;
  if (!ok_sizes) {
    fill_kernel<<<fill_blocks, 256, 0, stream>>>(out, 1000.f, out_size);
    return;
  }

  // ws: u 2MB + kfo 8.4 + vfo 8.4 + op 16.8 + mb/lb 0.5 = 36.6MB
  const size_t HND = (size_t)NHEAD * NROWS * DDIM;
  const size_t ND  = (size_t)NROWS * DDIM;
  const size_t need = ND * 4 + 2 * HND * 2 + 2 * HND * 2 + 2 * NHEAD * NROWS * 8;
  if (ws_size < need) {
    fill_kernel<<<fill_blocks, 256, 0, stream>>>(out, 500.f, out_size);
    return;
  }

  const float* x  = (const float*)d_in[0];
  const float* Wk = (const float*)d_in[1];
  const float* Wq = (const float*)d_in[2];
  const float* Wv = (const float*)d_in[3];
  const float* Wm = (const float*)d_in[4];
  const float* Wg = (const float*)d_in[5];
  const float* bg = (const float*)d_in[6];

  float*     u   = (float*)d_ws;
  _Float16*  kfo = (_Float16*)(u + ND);
  _Float16*  vfo = kfo + HND;
  _Float16*  op  = vfo + HND;
  float*     mb  = (float*)(op + 2 * HND);
  float*     lb  = mb + 2 * NHEAD * NROWS;

  (void)hipGetLastError();
  proj_kernel<<<dim3(64, NHEAD, 2), 256, 0, stream>>>(x, Wk, Wv, kfo, vfo);
  flash_kernel<<<dim3(512), 256, 0, stream>>>(x, Wq, kfo, vfo, op, mb, lb);
  merge_kernel<<<dim3(4096), 128, 0, stream>>>(op, mb, lb, Wm, u);
  mlp_kernel<<<dim3(64), 256, 0, stream>>>(x, u, Wg, bg, out);
  if (hipGetLastError() != hipSuccess) {
    fill_kernel<<<fill_blocks, 256, 0, stream>>>(out, 2000.f, out_size);
  }
}